// Round 10
// baseline (409.153 us; speedup 1.0000x reference)
//
#include <hip/hip_runtime.h>
#include <hip/hip_cooperative_groups.h>

namespace cg = cooperative_groups;

typedef _Float16 f16;
typedef _Float16 f16x8 __attribute__((ext_vector_type(8)));
typedef float    f32x4 __attribute__((ext_vector_type(4)));

// async global->LDS, 16B per lane; LDS dest = wave-uniform base + lane*16.
__device__ __forceinline__ void gld_lds16(const void* g, void* l) {
    __builtin_amdgcn_global_load_lds((__attribute__((address_space(1))) void*)g,
                                     (__attribute__((address_space(3))) void*)l,
                                     16, 0, 0);
}

// compiler-barrier-wrapped s_barrier: LDS/global ops must not migrate across.
#define BARRIER() do { asm volatile("" ::: "memory"); \
                       __builtin_amdgcn_s_barrier();  \
                       asm volatile("" ::: "memory"); } while (0)

// ---------------------------------------------------------------------------
// 8-phase 256x256xBK64 K-tile (QK engine). See r4-r9: no spill, vmcnt(2) only
// at end-ph1/ph4, loads never drain to 0 in the main loop.
// ---------------------------------------------------------------------------
template<bool STG, int VM1, int VM4>
__device__ __forceinline__ void tile256(
    f32x4 (&acc)[8][4],
    const f16* Ak0, const f16* Ak1, const f16* Bk0, const f16* Bk1,
    const f16* gAn, const f16* gBn, f16* lAn, f16* lBn, int lda, int ldb)
{
    {
        f16x8 a[4], b[4];
        #pragma unroll
        for (int mf = 0; mf < 4; mf++) a[mf] = *(const f16x8*)(Ak0 + mf * 1024);
        #pragma unroll
        for (int nf = 0; nf < 4; nf++) b[nf] = *(const f16x8*)(Bk0 + nf * 1024);
        if (STG) {
            gld_lds16(gBn,                  lBn);
            gld_lds16(gBn + (long)64 * ldb, lBn + 4096);
        }
        BARRIER();
        __builtin_amdgcn_s_setprio(1);
        #pragma unroll
        for (int mf = 0; mf < 4; mf++)
            #pragma unroll
            for (int nf = 0; nf < 4; nf++)
                acc[mf][nf] = __builtin_amdgcn_mfma_f32_16x16x32_f16(
                    a[mf], b[nf], acc[mf][nf], 0, 0, 0);
        __builtin_amdgcn_s_setprio(0);
        if (VM1 == 2)      asm volatile("s_waitcnt vmcnt(2)" ::: "memory");
        else if (VM1 == 0) asm volatile("s_waitcnt vmcnt(0)" ::: "memory");
        BARRIER();
        f16x8 a2[4];
        #pragma unroll
        for (int mf = 0; mf < 4; mf++) a2[mf] = *(const f16x8*)(Ak0 + (mf + 4) * 1024);
        if (STG) {
            gld_lds16(gBn + (long)128 * ldb, lBn + 8192);
            gld_lds16(gBn + (long)192 * ldb, lBn + 12288);
        }
        BARRIER();
        __builtin_amdgcn_s_setprio(1);
        #pragma unroll
        for (int mf = 0; mf < 4; mf++)
            #pragma unroll
            for (int nf = 0; nf < 4; nf++)
                acc[mf + 4][nf] = __builtin_amdgcn_mfma_f32_16x16x32_f16(
                    a2[mf], b[nf], acc[mf + 4][nf], 0, 0, 0);
        __builtin_amdgcn_s_setprio(0);
        BARRIER();
    }
    {
        f16x8 a[4], b[4];
        #pragma unroll
        for (int mf = 0; mf < 4; mf++) a[mf] = *(const f16x8*)(Ak1 + mf * 1024);
        #pragma unroll
        for (int nf = 0; nf < 4; nf++) b[nf] = *(const f16x8*)(Bk1 + nf * 1024);
        if (STG) {
            gld_lds16(gAn,                   lAn);
            gld_lds16(gAn + (long)128 * lda, lAn + 8192);
        }
        BARRIER();
        __builtin_amdgcn_s_setprio(1);
        #pragma unroll
        for (int mf = 0; mf < 4; mf++)
            #pragma unroll
            for (int nf = 0; nf < 4; nf++)
                acc[mf][nf] = __builtin_amdgcn_mfma_f32_16x16x32_f16(
                    a[mf], b[nf], acc[mf][nf], 0, 0, 0);
        __builtin_amdgcn_s_setprio(0);
        BARRIER();
        f16x8 a2[4];
        #pragma unroll
        for (int mf = 0; mf < 4; mf++) a2[mf] = *(const f16x8*)(Ak1 + (mf + 4) * 1024);
        if (STG) {
            gld_lds16(gAn + (long)64 * lda,  lAn + 4096);
            gld_lds16(gAn + (long)192 * lda, lAn + 12288);
        }
        BARRIER();
        __builtin_amdgcn_s_setprio(1);
        #pragma unroll
        for (int mf = 0; mf < 4; mf++)
            #pragma unroll
            for (int nf = 0; nf < 4; nf++)
                acc[mf + 4][nf] = __builtin_amdgcn_mfma_f32_16x16x32_f16(
                    a2[mf], b[nf], acc[mf + 4][nf], 0, 0, 0);
        __builtin_amdgcn_s_setprio(0);
        if (VM4 == 2)      asm volatile("s_waitcnt vmcnt(2)" ::: "memory");
        else if (VM4 == 0) asm volatile("s_waitcnt vmcnt(0)" ::: "memory");
        BARRIER();
    }
}

// QK 256^2 engine body. m = logical block id (0..255), XCD-chunk swizzled:
// XCD k gets 4 i-tiles x all 8 j-tiles -> B operand (4MB) fits its L2.
__device__ __forceinline__ void qk256(
    const f16* __restrict__ A, const f16* __restrict__ B, f16* __restrict__ C,
    int lda, int ldb, int ldc, f16* Lds, int tid, int m)
{
    const int L  = (m & 7) * 32 + (m >> 3);
    const int i0 = (L >> 3) * 256;
    const int j0 = (L & 7) * 256;

    const int lane = tid & 63;
    const int wave = tid >> 6;
    const int wm = wave >> 2, wn = wave & 3;
    const int row16 = lane & 15, quad = lane >> 4;
    const int swz = row16 & 7;

    const int c0 = (quad ^ swz) * 8;
    const int c1 = ((quad + 4) ^ swz) * 8;
    const f16* A0k0 = Lds + (wm * 128 + row16) * 64 + c0;
    const f16* A0k1 = Lds + (wm * 128 + row16) * 64 + c1;
    const f16* B0k0 = Lds + 16384 + (wn * 64 + row16) * 64 + c0;
    const f16* B0k1 = Lds + 16384 + (wn * 64 + row16) * 64 + c1;

    const int srow = tid >> 3;
    const int scol = ((tid & 7) ^ (srow & 7)) * 8;
    const f16* gA = A + (long)(i0 + srow) * lda + scol;
    const f16* gB = B + (long)(j0 + srow) * ldb + scol;
    f16* lA0 = Lds + tid * 8;
    f16* lB0 = Lds + 16384 + tid * 8;
    f16* lA1 = Lds + 32768 + tid * 8;
    f16* lB1 = Lds + 32768 + 16384 + tid * 8;

    gld_lds16(gB,                   lB0);
    gld_lds16(gB + (long)64 * ldb,  lB0 + 4096);
    gld_lds16(gB + (long)128 * ldb, lB0 + 8192);
    gld_lds16(gB + (long)192 * ldb, lB0 + 12288);
    gld_lds16(gA,                   lA0);
    gld_lds16(gA + (long)128 * lda, lA0 + 8192);
    gld_lds16(gA + (long)64 * lda,  lA0 + 4096);
    gld_lds16(gA + (long)192 * lda, lA0 + 12288);

    f32x4 acc[8][4] = {};

    asm volatile("s_waitcnt vmcnt(2)" ::: "memory");
    BARRIER();

    for (int t = 0; t < 14; t += 2) {
        tile256<true, 2, 2>(acc, A0k0, A0k1, B0k0, B0k1,
                            gA + (t + 1) * 64, gB + (t + 1) * 64,
                            lA1, lB1, lda, ldb);
        tile256<true, 2, 2>(acc, A0k0 + 32768, A0k1 + 32768,
                            B0k0 + 32768, B0k1 + 32768,
                            gA + (t + 2) * 64, gB + (t + 2) * 64,
                            lA0, lB0, lda, ldb);
    }
    tile256<true, 2, 2>(acc, A0k0, A0k1, B0k0, B0k1,
                        gA + 15 * 64, gB + 15 * 64, lA1, lB1, lda, ldb);
    tile256<false, 0, -1>(acc, A0k0 + 32768, A0k1 + 32768,
                          B0k0 + 32768, B0k1 + 32768,
                          nullptr, nullptr, nullptr, nullptr, lda, ldb);

    #pragma unroll
    for (int mf = 0; mf < 8; mf++) {
        const int r0 = i0 + wm * 128 + mf * 16 + quad * 4;
        #pragma unroll
        for (int nf = 0; nf < 4; nf++) {
            const int c = j0 + wn * 64 + nf * 16 + row16;
            #pragma unroll
            for (int r = 0; r < 4; r++)
                C[(long)(r0 + r) * ldc + c] = (f16)acc[mf][nf][r];
        }
    }
}

// ---------------------------------------------------------------------------
// 128x64x64 GEMM half-engine: identical to the proven gemm128_body but
// parameterized on a 24KB LDS region and a 256-thread index t, so two of
// them (waves 0-3 / 4-7) can run in lockstep inside a 512-thread block.
// All __syncthreads are executed by both halves (callers guarantee equal
// Keff / trip counts per iteration). Plain stores (atomics regressed, r8).
// ---------------------------------------------------------------------------
template<typename OutT>
__device__ __forceinline__ void gemm128_half(
    const f16* __restrict__ A, const f16* __restrict__ B, OutT* __restrict__ C,
    int lda, int ldb, int ldc, int Keff, float scale, int i0, int j0,
    f16* lds, int t)
{
    f16* As = lds;               // 128*64 f16 = 16KB
    f16* Bs = lds + 128 * 64;    // 64*64  f16 =  8KB

    const int lane = t & 63;
    const int wave = t >> 6;            // 0..3 within half
    const int row16 = lane & 15;
    const int quad  = lane >> 4;
    const int swz   = row16 & 7;
    const int wr = (wave >> 1) * 64;
    const int wc = (wave & 1) * 32;

    const int srow = t >> 3;                        // 0..31
    const int scol = ((t & 7) ^ (srow & 7)) * 8;    // swizzled global col
    const f16* gA = A + (long)(i0 + srow) * lda + scol;
    const f16* gB = B + (long)(j0 + srow) * ldb + scol;
    f16* lA = As + t * 8;
    f16* lB = Bs + t * 8;

    f32x4 acc[4][2] = {};

    for (int k0 = 0; k0 < Keff; k0 += 64) {
        gld_lds16(gA + k0,                  lA);
        gld_lds16(gA + k0 + (long)32 * lda, lA + 32 * 64);
        gld_lds16(gA + k0 + (long)64 * lda, lA + 64 * 64);
        gld_lds16(gA + k0 + (long)96 * lda, lA + 96 * 64);
        gld_lds16(gB + k0,                  lB);
        gld_lds16(gB + k0 + (long)32 * ldb, lB + 32 * 64);
        __syncthreads();

        #pragma unroll
        for (int kk = 0; kk < 2; kk++) {
            f16x8 af[4], bf[2];
            #pragma unroll
            for (int u = 0; u < 4; u++)
                af[u] = *(const f16x8*)(As + (wr + u * 16 + row16) * 64
                                           + (((kk * 4 + quad) ^ swz) * 8));
            #pragma unroll
            for (int u = 0; u < 2; u++)
                bf[u] = *(const f16x8*)(Bs + (wc + u * 16 + row16) * 64
                                           + (((kk * 4 + quad) ^ swz) * 8));
            #pragma unroll
            for (int mt = 0; mt < 4; mt++)
                #pragma unroll
                for (int nt = 0; nt < 2; nt++)
                    acc[mt][nt] = __builtin_amdgcn_mfma_f32_16x16x32_f16(
                        af[mt], bf[nt], acc[mt][nt], 0, 0, 0);
        }
        __syncthreads();
    }

    #pragma unroll
    for (int mt = 0; mt < 4; mt++) {
        const int r0 = i0 + wr + mt * 16 + quad * 4;
        #pragma unroll
        for (int nt = 0; nt < 2; nt++) {
            const int c = j0 + wc + nt * 16 + row16;
            #pragma unroll
            for (int r = 0; r < 4; r++)
                C[(long)(r0 + r) * ldc + c] = (OutT)(acc[mt][nt][r] * scale);
        }
    }
}

// ---------------------------------------------------------------------------
// MEGA-KERNEL: all 5 stages in one cooperative dispatch; grid.sync() replaces
// the 4 stream boundaries (~70-85 us of serialization at r9).
// grid = 256 blocks x 512 thr x 128KB LDS -> exactly 1 block/CU, co-resident.
// ---------------------------------------------------------------------------
__global__ void __launch_bounds__(512, 2)
attn_all(const float* __restrict__ x, const float* __restrict__ Wq,
         const float* __restrict__ Wk, const float* __restrict__ Wv,
         f16* __restrict__ xh, f16* __restrict__ wh,
         f16* __restrict__ QKh, f16* __restrict__ Vt,
         f16* __restrict__ Sc, float* __restrict__ out)
{
    cg::grid_group grid = cg::this_grid();
    __shared__ f16 Lds[65536] __attribute__((aligned(16)));   // 128 KiB

    const int bid = (int)blockIdx.x;   // 0..255
    const int tid = (int)threadIdx.x;  // 0..511
    const int h   = tid >> 8;          // half engine id (0/1)
    const int t   = tid & 255;         // index within half

    // ---- stage 0: fp32 -> fp16 convert (grid-stride; x then Wq|Wk|Wv) ----
    {
        const long base = (long)bid * 512 + tid;
        for (long c = base; c < 1048576; c += 131072) {    // x: 8.39M elems
            const long i = c * 8;
            f32x4 a = *(const f32x4*)(x + i);
            f32x4 b = *(const f32x4*)(x + i + 4);
            f16x8 o;
            o[0]=(f16)a[0]; o[1]=(f16)a[1]; o[2]=(f16)a[2]; o[3]=(f16)a[3];
            o[4]=(f16)b[0]; o[5]=(f16)b[1]; o[6]=(f16)b[2]; o[7]=(f16)b[3];
            *(f16x8*)(xh + i) = o;
        }
        for (long c = base; c < 393216; c += 131072) {     // weights: 3x1M
            const float* src;
            long off;
            if (c < 131072)      { src = Wq; off = c * 8; }
            else if (c < 262144) { src = Wk; off = (c - 131072) * 8; }
            else                 { src = Wv; off = (c - 262144) * 8; }
            f32x4 a = *(const f32x4*)(src + off);
            f32x4 b = *(const f32x4*)(src + off + 4);
            f16x8 o;
            o[0]=(f16)a[0]; o[1]=(f16)a[1]; o[2]=(f16)a[2]; o[3]=(f16)a[3];
            o[4]=(f16)b[0]; o[5]=(f16)b[1]; o[6]=(f16)b[2]; o[7]=(f16)b[3];
            *(f16x8*)(wh + c * 8) = o;     // wh = Wq|Wk|Wv contiguous
        }
    }
    grid.sync();

    // ---- stage 1: QK = x [Wq;Wk]^T via the 256^2 8-phase engine ----
    qk256(xh, wh, QKh, 1024, 1024, 2048, Lds, tid, bid);
    grid.sync();

    // ---- stage 2: V^T + Sc, two 128x64 half-engines per block ----
    // Per XCD (= bid&7): ordered tile list = [Vt chunk: 128] ++ [Sc chunk: 136]
    // = 264 tiles over 64 half-engines (le = (bid>>3)*2 + h), 4-5 trips each.
    // All tiles K=1024 -> both halves have identical barrier counts per trip.
    {
        const int xcd = bid & 7;
        const int le  = (bid >> 3) * 2 + h;    // 0..63 within XCD
        f16* myLds = Lds + h * 12288;          // 24KB per half
        const int trips = (le < 8) ? 5 : 4;    // 264 = 64*4 + 8 (same for h=0/1)
        for (int i = 0; i < trips; i++) {
            const int v = le + 64 * i;         // 0..263, bijective per XCD
            if (v < 128) {
                const int L = xcd * 128 + v;   // Vt: cols band per XCD
                gemm128_half<f16>(wh + 2L * 1048576, xh, Vt,
                                  1024, 1024, 8192, 1024, 1.f,
                                  (L & 7) * 128, (L >> 3) * 64, myLds, t);
            } else {
                const int L = xcd * 136 + (v - 128);   // Sc tri tile 0..1087
                const int z = L / 272;
                const int r = L - z * 272;
                int y = 0;
                while ((y + 1) * (y + 2) <= r) y++;
                const int xx = r - y * (y + 1);
                const long off = (long)z * (2048L * 2048);
                gemm128_half<f16>(QKh + off, QKh + 1024 + off, Sc + off,
                                  2048, 2048, 2048, 1024, 0.03125f,
                                  y * 128, xx * 64, myLds, t);
            }
            __syncthreads();
        }
    }
    grid.sync();

    // ---- stage 3: causal softmax, 2 rows per block per iteration ----
    {
        float* redm = (float*)Lds + h * 16;    // 4 floats
        float* reds = redm + 8;                // 4 floats
        for (int rp = 0; rp < 16; rp++) {
            const long rowg = (long)rp * 512 + bid * 2 + h;   // 0..8191
            const long b = rowg >> 11;
            const int  i = (int)(rowg & 2047);
            f16* row = Sc + ((b * 2048 + i) * 2048L);
            const int Lp = ((i >> 7) + 1) << 7;
            const int c0 = t * 8;
            const int lane = t & 63, wv = t >> 6;
            const bool act = c0 < Lp;

            float v[8];
            float m = -3.4e38f;
            if (act) {
                f16x8 in = *(const f16x8*)(row + c0);
                #pragma unroll
                for (int j = 0; j < 8; j++) {
                    const bool ok = (c0 + j) <= i;
                    v[j] = ok ? (float)in[j] : -3.4e38f;
                    m = fmaxf(m, v[j]);
                }
            }
            #pragma unroll
            for (int off = 32; off > 0; off >>= 1)
                m = fmaxf(m, __shfl_down(m, off, 64));
            if (lane == 0) redm[wv] = m;
            __syncthreads();
            const float m0 = fmaxf(fmaxf(redm[0], redm[1]),
                                   fmaxf(redm[2], redm[3]));

            float e[8];
            float s = 0.f;
            if (act) {
                #pragma unroll
                for (int j = 0; j < 8; j++) {
                    const bool ok = (c0 + j) <= i;
                    e[j] = ok ? __expf(v[j] - m0) : 0.f;
                    s += e[j];
                }
            }
            #pragma unroll
            for (int off = 32; off > 0; off >>= 1)
                s += __shfl_down(s, off, 64);
            if (lane == 0) reds[wv] = s;
            __syncthreads();
            const float inv = 1.f / (reds[0] + reds[1] + reds[2] + reds[3]);

            if (act) {
                f16x8 o;
                #pragma unroll
                for (int j = 0; j < 8; j++) o[j] = (f16)(e[j] * inv);
                *(f16x8*)(row + c0) = o;
            }
            __syncthreads();   // WAR: red arrays reused next iteration
        }
    }
    grid.sync();

    // ---- stage 4: PV, snake-paired for exact balance ----
    // 512 pairs (by,x2,z), halves take x = 2*x2+h (same Keff -> barriers ok).
    // Block b does pairs b and 511-b: Keff units (16-g)+(g+1) = 17, uniform.
    {
        f16* myLds = Lds + h * 12288;
        for (int it = 0; it < 2; it++) {
            const int p = it ? 511 - bid : bid;
            const int g = p >> 5;
            const int by = 15 - g;
            const int rem = p & 31;
            const int x2 = rem >> 2, z = rem & 3;
            const int i0 = by * 128;
            gemm128_half<float>(Sc + (long)z * (2048L * 2048),
                                Vt + (long)z * 2048,
                                out + (long)z * (2048L * 1024),
                                2048, 8192, 1024, i0 + 128, 1.f,
                                i0, (x2 * 2 + h) * 64, myLds, t);
            __syncthreads();
        }
    }
}

// ---------------------------------------------------------------------------
// Fallback path (round-9 5-kernel pipeline) in case cooperative launch is
// rejected under graph capture. Thin wrappers over the shared device bodies.
// ---------------------------------------------------------------------------
__global__ void __launch_bounds__(512, 2)
gemm256_k1024(const f16* __restrict__ A, const f16* __restrict__ B,
              f16* __restrict__ C, int lda, int ldb, int ldc)
{
    __shared__ f16 L[65536] __attribute__((aligned(16)));
    qk256(A, B, C, lda, ldb, ldc, L, (int)threadIdx.x, (int)blockIdx.x);
}

__global__ void __launch_bounds__(256)
gemm_vt_sc(const f16* __restrict__ xh, const f16* __restrict__ wvh,
           const f16* __restrict__ QKh, f16* __restrict__ Vt,
           f16* __restrict__ Sc)
{
    __shared__ f16 L[12288] __attribute__((aligned(16)));
    const int blk = (int)blockIdx.x;
    if (blk < 1024) {
        const int Lx = (blk & 7) * 128 + (blk >> 3);
        gemm128_half<f16>(wvh, xh, Vt, 1024, 1024, 8192, 1024, 1.f,
                          (Lx & 7) * 128, (Lx >> 3) * 64, L, (int)threadIdx.x);
    } else {
        const int m = blk - 1024;
        const int Lx = (m & 7) * 136 + (m >> 3);
        const int z = Lx / 272;
        const int r = Lx - z * 272;
        int y = 0;
        while ((y + 1) * (y + 2) <= r) y++;
        const int xx = r - y * (y + 1);
        const long off = (long)z * (2048L * 2048);
        gemm128_half<f16>(QKh + off, QKh + 1024 + off, Sc + off,
                          2048, 2048, 2048, 1024, 0.03125f,
                          y * 128, xx * 64, L, (int)threadIdx.x);
    }
}

__global__ void __launch_bounds__(256)
gemm_pv(const f16* __restrict__ Sc, const f16* __restrict__ Vt,
        float* __restrict__ out)
{
    __shared__ f16 L[12288] __attribute__((aligned(16)));
    const int n  = (int)blockIdx.x;
    const int by = 15 - (n >> 6);
    const int rem = n & 63;
    const int x  = rem >> 2;
    const int z  = rem & 3;
    const int i0 = by * 128;
    gemm128_half<float>(Sc + (long)z * (2048L * 2048),
                        Vt + (long)z * 2048,
                        out + (long)z * (2048L * 1024),
                        2048, 8192, 1024, i0 + 128, 1.f,
                        i0, x * 64, L, (int)threadIdx.x);
}

__global__ void __launch_bounds__(256)
softmax_causal(f16* __restrict__ Sc)
{
    const int S = 2048;
    const long rowg = blockIdx.x;
    const long b = rowg >> 11;
    const int  i = (int)(rowg & 2047);
    f16* row = Sc + ((b * S + i) * (long)S);
    const int L = ((i >> 7) + 1) << 7;

    const int tid = threadIdx.x;
    const int c0  = tid * 8;
    const int lane = tid & 63, wave = tid >> 6;
    const bool act = c0 < L;

    float v[8];
    float m = -3.4e38f;
    if (act) {
        f16x8 in = *(const f16x8*)(row + c0);
        #pragma unroll
        for (int j = 0; j < 8; j++) {
            const bool ok = (c0 + j) <= i;
            v[j] = ok ? (float)in[j] : -3.4e38f;
            m = fmaxf(m, v[j]);
        }
    }
    #pragma unroll
    for (int off = 32; off > 0; off >>= 1)
        m = fmaxf(m, __shfl_down(m, off, 64));
    __shared__ float redm[4];
    if (lane == 0) redm[wave] = m;
    __syncthreads();
    const float m0 = fmaxf(fmaxf(redm[0], redm[1]), fmaxf(redm[2], redm[3]));

    float e[8];
    float s = 0.f;
    if (act) {
        #pragma unroll
        for (int j = 0; j < 8; j++) {
            const bool ok = (c0 + j) <= i;
            e[j] = ok ? __expf(v[j] - m0) : 0.f;
            s += e[j];
        }
    }
    #pragma unroll
    for (int off = 32; off > 0; off >>= 1)
        s += __shfl_down(s, off, 64);
    __shared__ float reds[4];
    if (lane == 0) reds[wave] = s;
    __syncthreads();
    const float inv = 1.f / (reds[0] + reds[1] + reds[2] + reds[3]);

    if (act) {
        f16x8 o;
        #pragma unroll
        for (int j = 0; j < 8; j++) o[j] = (f16)(e[j] * inv);
        *(f16x8*)(row + c0) = o;
    }
}

__global__ void __launch_bounds__(256)
convert_all(const float* __restrict__ x, const float* __restrict__ Wq,
            const float* __restrict__ Wk, const float* __restrict__ Wv,
            f16* __restrict__ xh, f16* __restrict__ wh)
{
    const long blk = blockIdx.x;
    const float* src;
    f16* dst;
    long base;
    if (blk < 4096)      { src = x;  dst = xh;                    base = blk * 2048; }
    else if (blk < 4608) { src = Wq; dst = wh;                    base = (blk - 4096) * 2048; }
    else if (blk < 5120) { src = Wk; dst = wh + 1024L * 1024;     base = (blk - 4608) * 2048; }
    else                 { src = Wv; dst = wh + 2L * 1024 * 1024; base = (blk - 5120) * 2048; }
    const long i = base + (long)threadIdx.x * 8;
    f32x4 a = *(const f32x4*)(src + i);
    f32x4 b = *(const f32x4*)(src + i + 4);
    f16x8 o;
    o[0] = (f16)a[0]; o[1] = (f16)a[1]; o[2] = (f16)a[2]; o[3] = (f16)a[3];
    o[4] = (f16)b[0]; o[5] = (f16)b[1]; o[6] = (f16)b[2]; o[7] = (f16)b[3];
    *(f16x8*)(dst + i) = o;
}

extern "C" void kernel_launch(void* const* d_in, const int* in_sizes, int n_in,
                              void* d_out, int out_size, void* d_ws, size_t ws_size,
                              hipStream_t stream)
{
    (void)in_sizes; (void)n_in; (void)out_size; (void)ws_size;
    const float* x  = (const float*)d_in[0];
    const float* Wq = (const float*)d_in[1];
    const float* Wk = (const float*)d_in[2];
    const float* Wv = (const float*)d_in[3];
    float* out = (float*)d_out;

    const long NX = 4L * 2048 * 1024;   // B*S*E = 8388608
    const long NW = 1024L * 1024;

    char* p = (char*)d_ws;
    f16* xh  = (f16*)p; p += NX * 2;
    f16* wh  = (f16*)p; p += 3 * NW * 2;            // Wq | Wk | Wv contiguous
    f16* QKh = (f16*)p; p += 2 * NX * 2;            // [8192][2048]: Q | K cols
    f16* Vt  = (f16*)p; p += NX * 2;                // [E=1024][B*S=8192]
    f16* Sc  = (f16*)p; p += 4L * 2048 * 2048 * 2;  // scores -> P in place
    f16* wvh = wh + 2L * NW;

    void* args[] = { (void*)&x, (void*)&Wq, (void*)&Wk, (void*)&Wv,
                     (void*)&xh, (void*)&wh, (void*)&QKh, (void*)&Vt,
                     (void*)&Sc, (void*)&out };
    hipError_t err = hipLaunchCooperativeKernel(
        (const void*)attn_all, dim3(256), dim3(512), args, 0, stream);

    if (err != hipSuccess) {
        (void)hipGetLastError();   // clear sticky error; use r9 pipeline
        convert_all<<<5632, 256, 0, stream>>>(x, Wq, Wk, Wv, xh, wh);
        gemm256_k1024<<<256, 512, 0, stream>>>(xh, wh, QKh, 1024, 1024, 2048);
        gemm_vt_sc<<<2112, 256, 0, stream>>>(xh, wvh, QKh, Vt, Sc);
        softmax_causal<<<4 * 2048, 256, 0, stream>>>(Sc);
        gemm_pv<<<1024, 256, 0, stream>>>(Sc, Vt, out);
    }
}

// Round 11
// 221.457 us; speedup vs baseline: 1.8476x; 1.8476x over previous
//
#include <hip/hip_runtime.h>

typedef _Float16 f16;
typedef _Float16 f16x8 __attribute__((ext_vector_type(8)));
typedef float    f32x4 __attribute__((ext_vector_type(4)));

// async global->LDS, 16B per lane; LDS dest = wave-uniform base + lane*16.
// Global source address is per-lane arbitrary (we exploit this for swizzling).
__device__ __forceinline__ void gld_lds16(const void* g, void* l) {
    __builtin_amdgcn_global_load_lds((__attribute__((address_space(1))) void*)g,
                                     (__attribute__((address_space(3))) void*)l,
                                     16, 0, 0);
}

// compiler-barrier-wrapped s_barrier: LDS/global ops must not migrate across.
#define BARRIER() do { asm volatile("" ::: "memory"); \
                       __builtin_amdgcn_s_barrier();  \
                       asm volatile("" ::: "memory"); } while (0)

// ---------------------------------------------------------------------------
// 8-phase 256x256xBK64 GEMM (C = A * B^T, f16 out), K = 1024 (16 K-tiles).
// 512 thr = 8 waves (2Mx4N); per-wave 128x64 output = acc[8][4] 16x16 frags.
// LDS: 2 buffers x (A 256x64 + B 256x64) f16 = 128 KiB, XOR-chunk swizzled.
// Per K-tile t (reads buf[t&1]; stages tile t+1 into buf[(t+1)&1]). 4 phases,
// 16 MFMA each; fragment reads are per-phase (peak ~10 live frags, no spill).
// vmcnt(2) at end-ph1/ph4 only: loads never drain to 0 in the main loop.
// NOTE (r10): this engine is structurally fine at 1 block/CU; the 128x64
// engine below is NOT (needs 6+ blocks/CU of cross-block TLP) — do not fuse
// it into lockstep half-pairs (mega-kernel regressed 327 us vs sum 133).
// ---------------------------------------------------------------------------
template<bool STG, int VM1, int VM4>
__device__ __forceinline__ void tile256(
    f32x4 (&acc)[8][4],
    const f16* Ak0, const f16* Ak1, const f16* Bk0, const f16* Bk1,
    const f16* gAn, const f16* gBn,   // next-tile global bases (k-adjusted)
    f16* lAn, f16* lBn,               // next-tile LDS dests (other buffer)
    int lda, int ldb)
{
    // ---- phase 1: kk0, m-frags 0-3 ----
    {
        f16x8 a[4], b[4];
        #pragma unroll
        for (int mf = 0; mf < 4; mf++) a[mf] = *(const f16x8*)(Ak0 + mf * 1024);
        #pragma unroll
        for (int nf = 0; nf < 4; nf++) b[nf] = *(const f16x8*)(Bk0 + nf * 1024);
        if (STG) {
            gld_lds16(gBn,                  lBn);
            gld_lds16(gBn + (long)64 * ldb, lBn + 4096);
        }
        BARRIER();
        __builtin_amdgcn_s_setprio(1);
        #pragma unroll
        for (int mf = 0; mf < 4; mf++)
            #pragma unroll
            for (int nf = 0; nf < 4; nf++)
                acc[mf][nf] = __builtin_amdgcn_mfma_f32_16x16x32_f16(
                    a[mf], b[nf], acc[mf][nf], 0, 0, 0);
        __builtin_amdgcn_s_setprio(0);
        if (VM1 == 2)      asm volatile("s_waitcnt vmcnt(2)" ::: "memory");
        else if (VM1 == 0) asm volatile("s_waitcnt vmcnt(0)" ::: "memory");
        BARRIER();
        // ---- phase 2: kk0, m-frags 4-7 (b still live) ----
        f16x8 a2[4];
        #pragma unroll
        for (int mf = 0; mf < 4; mf++) a2[mf] = *(const f16x8*)(Ak0 + (mf + 4) * 1024);
        if (STG) {
            gld_lds16(gBn + (long)128 * ldb, lBn + 8192);
            gld_lds16(gBn + (long)192 * ldb, lBn + 12288);
        }
        BARRIER();
        __builtin_amdgcn_s_setprio(1);
        #pragma unroll
        for (int mf = 0; mf < 4; mf++)
            #pragma unroll
            for (int nf = 0; nf < 4; nf++)
                acc[mf + 4][nf] = __builtin_amdgcn_mfma_f32_16x16x32_f16(
                    a2[mf], b[nf], acc[mf + 4][nf], 0, 0, 0);
        __builtin_amdgcn_s_setprio(0);
        BARRIER();
    }
    // ---- phase 3: kk1, m-frags 0-3 ----
    {
        f16x8 a[4], b[4];
        #pragma unroll
        for (int mf = 0; mf < 4; mf++) a[mf] = *(const f16x8*)(Ak1 + mf * 1024);
        #pragma unroll
        for (int nf = 0; nf < 4; nf++) b[nf] = *(const f16x8*)(Bk1 + nf * 1024);
        if (STG) {
            gld_lds16(gAn,                   lAn);
            gld_lds16(gAn + (long)128 * lda, lAn + 8192);
        }
        BARRIER();
        __builtin_amdgcn_s_setprio(1);
        #pragma unroll
        for (int mf = 0; mf < 4; mf++)
            #pragma unroll
            for (int nf = 0; nf < 4; nf++)
                acc[mf][nf] = __builtin_amdgcn_mfma_f32_16x16x32_f16(
                    a[mf], b[nf], acc[mf][nf], 0, 0, 0);
        __builtin_amdgcn_s_setprio(0);
        BARRIER();
        // ---- phase 4: kk1, m-frags 4-7 ----
        f16x8 a2[4];
        #pragma unroll
        for (int mf = 0; mf < 4; mf++) a2[mf] = *(const f16x8*)(Ak1 + (mf + 4) * 1024);
        if (STG) {
            gld_lds16(gAn + (long)64 * lda,  lAn + 4096);
            gld_lds16(gAn + (long)192 * lda, lAn + 12288);
        }
        BARRIER();
        __builtin_amdgcn_s_setprio(1);
        #pragma unroll
        for (int mf = 0; mf < 4; mf++)
            #pragma unroll
            for (int nf = 0; nf < 4; nf++)
                acc[mf + 4][nf] = __builtin_amdgcn_mfma_f32_16x16x32_f16(
                    a2[mf], b[nf], acc[mf + 4][nf], 0, 0, 0);
        __builtin_amdgcn_s_setprio(0);
        if (VM4 == 2)      asm volatile("s_waitcnt vmcnt(2)" ::: "memory");
        else if (VM4 == 0) asm volatile("s_waitcnt vmcnt(0)" ::: "memory");
        BARRIER();
    }
}

// grid = 256 1-D blocks. XCD-chunk swizzle (T1): XCD k gets 32 consecutive
// logical tiles = 4 i-tiles x all 8 j-tiles, so the full B operand (4 MB)
// exactly fits that XCD's L2 and A-panels are fetched once per XCD.
__global__ void __launch_bounds__(512, 2)
gemm256_k1024(const f16* __restrict__ A, const f16* __restrict__ B,
              f16* __restrict__ C, int lda, int ldb, int ldc)
{
    const int m  = (int)blockIdx.x;            // 0..255
    const int L  = (m & 7) * 32 + (m >> 3);    // bijective: 256 = 8*32
    const int i0 = (L >> 3) * 256;             // 32 i-tiles
    const int j0 = (L & 7) * 256;              // 8 j-tiles

    __shared__ f16 Lds[2 * 32768] __attribute__((aligned(16)));

    const int tid  = threadIdx.x;
    const int lane = tid & 63;
    const int wave = tid >> 6;
    const int wm = wave >> 2, wn = wave & 3;
    const int row16 = lane & 15, quad = lane >> 4;
    const int swz = row16 & 7;

    // per-thread LDS read bases (buf0; buf1 = +32768). chunk XOR-deswizzle:
    // LDS[row][cb] holds global chunk cb^(row&7) -> read chunk (k-chunk ^ swz).
    const int c0 = (quad ^ swz) * 8;           // kk0 chunk
    const int c1 = ((quad + 4) ^ swz) * 8;     // kk1 chunk
    const f16* A0k0 = Lds + (wm * 128 + row16) * 64 + c0;
    const f16* A0k1 = Lds + (wm * 128 + row16) * 64 + c1;
    const f16* B0k0 = Lds + 16384 + (wn * 64 + row16) * 64 + c0;
    const f16* B0k1 = Lds + 16384 + (wn * 64 + row16) * 64 + c1;

    // staging: 512 thr x 16B cover one 64-row quarter (64x64 f16) per issue.
    const int srow = tid >> 3;                       // 0..63
    const int scol = ((tid & 7) ^ (srow & 7)) * 8;   // swizzled global col
    const f16* gA = A + (long)(i0 + srow) * lda + scol;
    const f16* gB = B + (long)(j0 + srow) * ldb + scol;
    f16* lA0 = Lds + tid * 8;
    f16* lB0 = Lds + 16384 + tid * 8;
    f16* lA1 = Lds + 32768 + tid * 8;
    f16* lB1 = Lds + 32768 + 16384 + tid * 8;

    // prologue: tile 0 -> buf0, issue order = steady staging order:
    // Bq0,Bq1,Bq2,Bq3,Aq0,Aq2,Aq1,Aq3; vmcnt(2) keeps Aq1,Aq3 in flight.
    gld_lds16(gB,                   lB0);
    gld_lds16(gB + (long)64 * ldb,  lB0 + 4096);
    gld_lds16(gB + (long)128 * ldb, lB0 + 8192);
    gld_lds16(gB + (long)192 * ldb, lB0 + 12288);
    gld_lds16(gA,                   lA0);
    gld_lds16(gA + (long)128 * lda, lA0 + 8192);
    gld_lds16(gA + (long)64 * lda,  lA0 + 4096);
    gld_lds16(gA + (long)192 * lda, lA0 + 12288);

    f32x4 acc[8][4] = {};

    asm volatile("s_waitcnt vmcnt(2)" ::: "memory");
    BARRIER();

    // 16 K-tiles: 7 steady pairs (tiles 0-13) + tile 14 (last stage) + tile 15
    for (int t = 0; t < 14; t += 2) {
        tile256<true, 2, 2>(acc, A0k0, A0k1, B0k0, B0k1,
                            gA + (t + 1) * 64, gB + (t + 1) * 64,
                            lA1, lB1, lda, ldb);
        tile256<true, 2, 2>(acc, A0k0 + 32768, A0k1 + 32768,
                            B0k0 + 32768, B0k1 + 32768,
                            gA + (t + 2) * 64, gB + (t + 2) * 64,
                            lA0, lB0, lda, ldb);
    }
    tile256<true, 2, 2>(acc, A0k0, A0k1, B0k0, B0k1,
                        gA + 15 * 64, gB + 15 * 64, lA1, lB1, lda, ldb);
    tile256<false, 0, -1>(acc, A0k0 + 32768, A0k1 + 32768,
                          B0k0 + 32768, B0k1 + 32768,
                          nullptr, nullptr, nullptr, nullptr, lda, ldb);

    // epilogue: C[row][col], col = lane&15, row = quad*4 + reg
    #pragma unroll
    for (int mf = 0; mf < 8; mf++) {
        const int r0 = i0 + wm * 128 + mf * 16 + quad * 4;
        #pragma unroll
        for (int nf = 0; nf < 4; nf++) {
            const int c = j0 + wn * 64 + nf * 16 + row16;
            #pragma unroll
            for (int r = 0; r < 4; r++)
                C[(long)(r0 + r) * ldc + c] = (f16)acc[mf][nf][r];
        }
    }
}

// ---------------------------------------------------------------------------
// 128x64x64 GEMM body, shared by the merged Vt+scores kernel and PV.
// 4 waves 2x2, each wave 64x32 out (acc[4][2]); ~48 VGPR / 24KB LDS -> 6+
// blocks/CU; cross-block overlap hides the 2-barrier drain stall.
// (r8: split-K atomics regressed 1.7x. r10: 1-block/CU lockstep fusion
//  regressed 2.5x. This engine lives and dies by independent-block TLP.)
// __shared__ here is a single module-level LDS allocation: calling this
// twice sequentially in one kernel reuses the same 24KB (occupancy intact).
// ---------------------------------------------------------------------------
template<typename OutT>
__device__ __forceinline__ void gemm128_body(
    const f16* __restrict__ A, const f16* __restrict__ B, OutT* __restrict__ C,
    int lda, int ldb, int ldc, int Keff, float scale, int i0, int j0)
{
    __shared__ f16 As[128 * 64] __attribute__((aligned(16)));
    __shared__ f16 Bs[64 * 64]  __attribute__((aligned(16)));

    const int tid  = threadIdx.x;
    const int lane = tid & 63;
    const int wave = tid >> 6;
    const int row16 = lane & 15;
    const int quad  = lane >> 4;
    const int swz   = row16 & 7;
    const int wr = (wave >> 1) * 64;   // wave row offset: 0 / 64
    const int wc = (wave & 1) * 32;    // wave col offset: 0 / 32

    const int srow = tid >> 3;                       // 0..31
    const int scol = ((tid & 7) ^ (srow & 7)) * 8;   // swizzled global col
    const f16* gA = A + (long)(i0 + srow) * lda + scol;
    const f16* gB = B + (long)(j0 + srow) * ldb + scol;
    f16* lA = As + tid * 8;   // + p*32*64
    f16* lB = Bs + tid * 8;

    f32x4 acc[4][2] = {};

    for (int k0 = 0; k0 < Keff; k0 += 64) {
        gld_lds16(gA + k0,                  lA);
        gld_lds16(gA + k0 + (long)32 * lda, lA + 32 * 64);
        gld_lds16(gA + k0 + (long)64 * lda, lA + 64 * 64);
        gld_lds16(gA + k0 + (long)96 * lda, lA + 96 * 64);
        gld_lds16(gB + k0,                  lB);
        gld_lds16(gB + k0 + (long)32 * ldb, lB + 32 * 64);
        __syncthreads();

        #pragma unroll
        for (int kk = 0; kk < 2; kk++) {
            f16x8 af[4], bf[2];
            #pragma unroll
            for (int t = 0; t < 4; t++)
                af[t] = *(const f16x8*)(As + (wr + t * 16 + row16) * 64
                                           + (((kk * 4 + quad) ^ swz) * 8));
            #pragma unroll
            for (int t = 0; t < 2; t++)
                bf[t] = *(const f16x8*)(Bs + (wc + t * 16 + row16) * 64
                                           + (((kk * 4 + quad) ^ swz) * 8));
            #pragma unroll
            for (int mt = 0; mt < 4; mt++)
                #pragma unroll
                for (int nt = 0; nt < 2; nt++)
                    acc[mt][nt] = __builtin_amdgcn_mfma_f32_16x16x32_f16(
                        af[mt], bf[nt], acc[mt][nt], 0, 0, 0);
        }
        __syncthreads();
    }

    // epilogue: C[row][col], col = lane&15, row = quad*4 + reg
    #pragma unroll
    for (int mt = 0; mt < 4; mt++) {
        const int r0 = i0 + wr + mt * 16 + quad * 4;
        #pragma unroll
        for (int nt = 0; nt < 2; nt++) {
            const int c = j0 + wc + nt * 16 + row16;
            #pragma unroll
            for (int r = 0; r < 4; r++)
                C[(long)(r0 + r) * ldc + c] = (OutT)(acc[mt][nt][r] * scale);
        }
    }
}

// Merged V^T + scores dispatch: 2112 uniform-work blocks (K=1024), with
// XCD-chunk swizzles (T1) so panel-sharing blocks land on one XCD's L2:
//  blocks [0,1024): V^T = Wv x^T. Logical order i-inner/j-outer (L = j*8+i);
//    chunk 128 logical tiles per XCD -> each xh B-panel (128KB, shared by the
//    8 i-blocks) is consumed within one XCD; wvh (2MB) is L2-resident.
//  blocks [1024,2112): Sc = Q K^T / 32, lower-tri 64-wide tiles (272/batch,
//    row-band-major); chunk 136 per XCD -> Q-panels fetched once per XCD.
// Measured at the 128-engine structural floor (49.3 us, FETCH 47MB, r7/r9).
__global__ void __launch_bounds__(256)
gemm_vt_sc(const f16* __restrict__ xh, const f16* __restrict__ wvh,
           const f16* __restrict__ QKh, f16* __restrict__ Vt,
           f16* __restrict__ Sc)
{
    const int blk = (int)blockIdx.x;
    if (blk < 1024) {
        const int L = (blk & 7) * 128 + (blk >> 3);   // bijective: 1024 = 8*128
        const int j = L >> 3;                          // 0..127 (col tile)
        const int i = L & 7;                           // 0..7   (row tile)
        gemm128_body<f16>(wvh, xh, Vt, 1024, 1024, 8192, 1024, 1.f,
                          i * 128, j * 64);
    } else {
        const int m = blk - 1024;                      // 0..1087
        const int L = (m & 7) * 136 + (m >> 3);        // bijective: 1088 = 8*136
        const int z = L / 272;                         // batch
        const int r = L - z * 272;
        int y = 0;
        while ((y + 1) * (y + 2) <= r) y++;            // cum(y) = y(y+1); r <= 271
        const int x = r - y * (y + 1);
        const long off = (long)z * (2048L * 2048);
        gemm128_body<f16>(QKh + off, QKh + 1024 + off, Sc + off,
                          2048, 2048, 2048, 1024, 0.03125f, y * 128, x * 64);
    }
}

// PV, exactly-balanced pairs: O = P V. 512 blocks; block b runs tiles b and
// 1023-b under the r9 LPT decode (by=15-(n>>6), x=(n&63)>>2, z=n&3).
// Pair K-units: (16-g)+(g+1) = 17 for every block -> 34 units/CU, uniform
// (greedy LPT's makespan was ~36). Big tile first, small second. Both calls
// reuse the same 24KB LDS; the K-loop's trailing __syncthreads drains reads
// before the second tile's staging (plus an explicit barrier for safety).
__global__ void __launch_bounds__(256)
gemm_pv(const f16* __restrict__ Sc, const f16* __restrict__ Vt,
        float* __restrict__ out)
{
    const int b = (int)blockIdx.x;       // 0..511
    #pragma unroll
    for (int it = 0; it < 2; it++) {
        const int n  = it ? 1023 - b : b;
        const int by = 15 - (n >> 6);
        const int rem = n & 63;
        const int x  = rem >> 2;             // 0..15
        const int z  = rem & 3;              // 0..3
        const int i0 = by * 128;
        gemm128_body<float>(Sc + (long)z * (2048L * 2048),
                            Vt + (long)z * 2048,
                            out + (long)z * (2048L * 1024),
                            2048, 8192, 1024, i0 + 128, 1.f, i0, x * 64);
        __syncthreads();
    }
}

// in-place causal softmax over fp16 scores; one block per row, 256 thr x 8 cols.
// Only the live prefix L = ((i>>7)+1)*128 is read/written.
__global__ void __launch_bounds__(256)
softmax_causal(f16* __restrict__ Sc)
{
    const int S = 2048;
    const long rowg = blockIdx.x;
    const long b = rowg >> 11;
    const int  i = (int)(rowg & 2047);
    f16* row = Sc + ((b * S + i) * (long)S);
    const int L = ((i >> 7) + 1) << 7;   // tile-aligned live row length

    const int tid = threadIdx.x;
    const int c0  = tid * 8;
    const int lane = tid & 63, wave = tid >> 6;
    const bool act = c0 < L;

    float v[8];
    float m = -3.4e38f;
    if (act) {
        f16x8 in = *(const f16x8*)(row + c0);
        #pragma unroll
        for (int j = 0; j < 8; j++) {
            const bool ok = (c0 + j) <= i;
            v[j] = ok ? (float)in[j] : -3.4e38f;
            m = fmaxf(m, v[j]);
        }
    }
    #pragma unroll
    for (int off = 32; off > 0; off >>= 1)
        m = fmaxf(m, __shfl_down(m, off, 64));
    __shared__ float redm[4];
    if (lane == 0) redm[wave] = m;
    __syncthreads();
    const float m0 = fmaxf(fmaxf(redm[0], redm[1]), fmaxf(redm[2], redm[3]));

    float e[8];
    float s = 0.f;
    if (act) {
        #pragma unroll
        for (int j = 0; j < 8; j++) {
            const bool ok = (c0 + j) <= i;
            e[j] = ok ? __expf(v[j] - m0) : 0.f;
            s += e[j];
        }
    }
    #pragma unroll
    for (int off = 32; off > 0; off >>= 1)
        s += __shfl_down(s, off, 64);
    __shared__ float reds[4];
    if (lane == 0) reds[wave] = s;
    __syncthreads();
    const float inv = 1.f / (reds[0] + reds[1] + reds[2] + reds[3]);

    if (act) {
        f16x8 o;
        #pragma unroll
        for (int j = 0; j < 8; j++) o[j] = (f16)(e[j] * inv);
        *(f16x8*)(row + c0) = o;
    }
}

// fused fp32->fp16 of x, Wq, Wk, Wv in one dispatch.
__global__ void __launch_bounds__(256)
convert_all(const float* __restrict__ x, const float* __restrict__ Wq,
            const float* __restrict__ Wk, const float* __restrict__ Wv,
            f16* __restrict__ xh, f16* __restrict__ wh)
{
    const long blk = blockIdx.x;
    const float* src;
    f16* dst;
    long base;
    if (blk < 4096)      { src = x;  dst = xh;                    base = blk * 2048; }
    else if (blk < 4608) { src = Wq; dst = wh;                    base = (blk - 4096) * 2048; }
    else if (blk < 5120) { src = Wk; dst = wh + 1024L * 1024;     base = (blk - 4608) * 2048; }
    else                 { src = Wv; dst = wh + 2L * 1024 * 1024; base = (blk - 5120) * 2048; }
    const long i = base + (long)threadIdx.x * 8;
    f32x4 a = *(const f32x4*)(src + i);
    f32x4 b = *(const f32x4*)(src + i + 4);
    f16x8 o;
    o[0] = (f16)a[0]; o[1] = (f16)a[1]; o[2] = (f16)a[2]; o[3] = (f16)a[3];
    o[4] = (f16)b[0]; o[5] = (f16)b[1]; o[6] = (f16)b[2]; o[7] = (f16)b[3];
    *(f16x8*)(dst + i) = o;
}

extern "C" void kernel_launch(void* const* d_in, const int* in_sizes, int n_in,
                              void* d_out, int out_size, void* d_ws, size_t ws_size,
                              hipStream_t stream)
{
    (void)in_sizes; (void)n_in; (void)out_size; (void)ws_size;
    const float* x  = (const float*)d_in[0];
    const float* Wq = (const float*)d_in[1];
    const float* Wk = (const float*)d_in[2];
    const float* Wv = (const float*)d_in[3];
    float* out = (float*)d_out;

    const long NX = 4L * 2048 * 1024;   // B*S*E = 8388608
    const long NW = 1024L * 1024;

    char* p = (char*)d_ws;
    f16* xh  = (f16*)p; p += NX * 2;
    f16* wh  = (f16*)p; p += 3 * NW * 2;            // Wq | Wk | Wv contiguous
    f16* QKh = (f16*)p; p += 2 * NX * 2;            // [8192][2048]: Q cols | K cols
    f16* Vt  = (f16*)p; p += NX * 2;                // [E=1024][B*S=8192]
    f16* Sc  = (f16*)p; p += 4L * 2048 * 2048 * 2;  // scores -> P in place
    f16* wvh = wh + 2L * NW;

    convert_all<<<5632, 256, 0, stream>>>(x, Wq, Wk, Wv, xh, wh);

    // QK = x [Wq;Wk]^T : [8192,2048] via 8-phase 256^2, XCD-chunk swizzled
    gemm256_k1024<<<256, 512, 0, stream>>>(
        xh, wh, QKh, 1024, 1024, 2048);

    // merged: V^T (1024 blocks) + Sc lower-tri (1088 blocks), XCD-chunked
    gemm_vt_sc<<<2112, 256, 0, stream>>>(xh, wvh, QKh, Vt, Sc);

    // causal softmax in place (live prefix only)
    softmax_causal<<<4 * 2048, 256, 0, stream>>>(Sc);

    // O = P V, exactly-balanced 17-unit pairs (512 blocks)
    gemm_pv<<<512, 256, 0, stream>>>(Sc, Vt, out);
}

// Round 12
// 219.452 us; speedup vs baseline: 1.8644x; 1.0091x over previous
//
#include <hip/hip_runtime.h>

typedef _Float16 f16;
typedef _Float16 f16x8 __attribute__((ext_vector_type(8)));
typedef float    f32x4 __attribute__((ext_vector_type(4)));

// async global->LDS, 16B per lane; LDS dest = wave-uniform base + lane*16.
// Global source address is per-lane arbitrary (we exploit this for swizzling).
__device__ __forceinline__ void gld_lds16(const void* g, void* l) {
    __builtin_amdgcn_global_load_lds((__attribute__((address_space(1))) void*)g,
                                     (__attribute__((address_space(3))) void*)l,
                                     16, 0, 0);
}

// compiler-barrier-wrapped s_barrier: LDS/global ops must not migrate across.
#define BARRIER() do { asm volatile("" ::: "memory"); \
                       __builtin_amdgcn_s_barrier();  \
                       asm volatile("" ::: "memory"); } while (0)

// ---------------------------------------------------------------------------
// 8-phase 256x256xBK64 GEMM (C = A * B^T, f16 out), K = 1024 (16 K-tiles).
// 512 thr = 8 waves (2Mx4N); per-wave 128x64 output = acc[8][4] 16x16 frags.
// LDS: 2 buffers x (A 256x64 + B 256x64) f16 = 128 KiB, XOR-chunk swizzled.
// Per K-tile t (reads buf[t&1]; stages tile t+1 into buf[(t+1)&1]). 4 phases,
// 16 MFMA each; fragment reads are per-phase (peak ~10 live frags, no spill).
// vmcnt(2) at end-ph1/ph4 only: loads never drain to 0 in the main loop.
// ---------------------------------------------------------------------------
template<bool STG, int VM1, int VM4>
__device__ __forceinline__ void tile256(
    f32x4 (&acc)[8][4],
    const f16* Ak0, const f16* Ak1, const f16* Bk0, const f16* Bk1,
    const f16* gAn, const f16* gBn,   // next-tile global bases (k-adjusted)
    f16* lAn, f16* lBn,               // next-tile LDS dests (other buffer)
    int lda, int ldb)
{
    // ---- phase 1: kk0, m-frags 0-3 ----
    {
        f16x8 a[4], b[4];
        #pragma unroll
        for (int mf = 0; mf < 4; mf++) a[mf] = *(const f16x8*)(Ak0 + mf * 1024);
        #pragma unroll
        for (int nf = 0; nf < 4; nf++) b[nf] = *(const f16x8*)(Bk0 + nf * 1024);
        if (STG) {
            gld_lds16(gBn,                  lBn);
            gld_lds16(gBn + (long)64 * ldb, lBn + 4096);
        }
        BARRIER();
        __builtin_amdgcn_s_setprio(1);
        #pragma unroll
        for (int mf = 0; mf < 4; mf++)
            #pragma unroll
            for (int nf = 0; nf < 4; nf++)
                acc[mf][nf] = __builtin_amdgcn_mfma_f32_16x16x32_f16(
                    a[mf], b[nf], acc[mf][nf], 0, 0, 0);
        __builtin_amdgcn_s_setprio(0);
        if (VM1 == 2)      asm volatile("s_waitcnt vmcnt(2)" ::: "memory");
        else if (VM1 == 0) asm volatile("s_waitcnt vmcnt(0)" ::: "memory");
        BARRIER();
        // ---- phase 2: kk0, m-frags 4-7 (b still live) ----
        f16x8 a2[4];
        #pragma unroll
        for (int mf = 0; mf < 4; mf++) a2[mf] = *(const f16x8*)(Ak0 + (mf + 4) * 1024);
        if (STG) {
            gld_lds16(gBn + (long)128 * ldb, lBn + 8192);
            gld_lds16(gBn + (long)192 * ldb, lBn + 12288);
        }
        BARRIER();
        __builtin_amdgcn_s_setprio(1);
        #pragma unroll
        for (int mf = 0; mf < 4; mf++)
            #pragma unroll
            for (int nf = 0; nf < 4; nf++)
                acc[mf + 4][nf] = __builtin_amdgcn_mfma_f32_16x16x32_f16(
                    a2[mf], b[nf], acc[mf + 4][nf], 0, 0, 0);
        __builtin_amdgcn_s_setprio(0);
        BARRIER();
    }
    // ---- phase 3: kk1, m-frags 0-3 ----
    {
        f16x8 a[4], b[4];
        #pragma unroll
        for (int mf = 0; mf < 4; mf++) a[mf] = *(const f16x8*)(Ak1 + mf * 1024);
        #pragma unroll
        for (int nf = 0; nf < 4; nf++) b[nf] = *(const f16x8*)(Bk1 + nf * 1024);
        if (STG) {
            gld_lds16(gAn,                   lAn);
            gld_lds16(gAn + (long)128 * lda, lAn + 8192);
        }
        BARRIER();
        __builtin_amdgcn_s_setprio(1);
        #pragma unroll
        for (int mf = 0; mf < 4; mf++)
            #pragma unroll
            for (int nf = 0; nf < 4; nf++)
                acc[mf][nf] = __builtin_amdgcn_mfma_f32_16x16x32_f16(
                    a[mf], b[nf], acc[mf][nf], 0, 0, 0);
        __builtin_amdgcn_s_setprio(0);
        BARRIER();
        // ---- phase 4: kk1, m-frags 4-7 ----
        f16x8 a2[4];
        #pragma unroll
        for (int mf = 0; mf < 4; mf++) a2[mf] = *(const f16x8*)(Ak1 + (mf + 4) * 1024);
        if (STG) {
            gld_lds16(gAn + (long)64 * lda,  lAn + 4096);
            gld_lds16(gAn + (long)192 * lda, lAn + 12288);
        }
        BARRIER();
        __builtin_amdgcn_s_setprio(1);
        #pragma unroll
        for (int mf = 0; mf < 4; mf++)
            #pragma unroll
            for (int nf = 0; nf < 4; nf++)
                acc[mf + 4][nf] = __builtin_amdgcn_mfma_f32_16x16x32_f16(
                    a2[mf], b[nf], acc[mf + 4][nf], 0, 0, 0);
        __builtin_amdgcn_s_setprio(0);
        if (VM4 == 2)      asm volatile("s_waitcnt vmcnt(2)" ::: "memory");
        else if (VM4 == 0) asm volatile("s_waitcnt vmcnt(0)" ::: "memory");
        BARRIER();
    }
}

// grid = 256 1-D blocks. XCD-chunk swizzle (T1): XCD k gets 32 consecutive
// logical tiles = 4 i-tiles x all 8 j-tiles, so the full B operand (4 MB)
// exactly fits that XCD's L2 and A-panels are fetched once per XCD.
__global__ void __launch_bounds__(512, 2)
gemm256_k1024(const f16* __restrict__ A, const f16* __restrict__ B,
              f16* __restrict__ C, int lda, int ldb, int ldc)
{
    const int m  = (int)blockIdx.x;            // 0..255
    const int L  = (m & 7) * 32 + (m >> 3);    // bijective: 256 = 8*32
    const int i0 = (L >> 3) * 256;             // 32 i-tiles
    const int j0 = (L & 7) * 256;              // 8 j-tiles

    __shared__ f16 Lds[2 * 32768] __attribute__((aligned(16)));

    const int tid  = threadIdx.x;
    const int lane = tid & 63;
    const int wave = tid >> 6;
    const int wm = wave >> 2, wn = wave & 3;
    const int row16 = lane & 15, quad = lane >> 4;
    const int swz = row16 & 7;

    // per-thread LDS read bases (buf0; buf1 = +32768). chunk XOR-deswizzle:
    // LDS[row][cb] holds global chunk cb^(row&7) -> read chunk (k-chunk ^ swz).
    const int c0 = (quad ^ swz) * 8;           // kk0 chunk
    const int c1 = ((quad + 4) ^ swz) * 8;     // kk1 chunk
    const f16* A0k0 = Lds + (wm * 128 + row16) * 64 + c0;
    const f16* A0k1 = Lds + (wm * 128 + row16) * 64 + c1;
    const f16* B0k0 = Lds + 16384 + (wn * 64 + row16) * 64 + c0;
    const f16* B0k1 = Lds + 16384 + (wn * 64 + row16) * 64 + c1;

    // staging: 512 thr x 16B cover one 64-row quarter (64x64 f16) per issue.
    const int srow = tid >> 3;                       // 0..63
    const int scol = ((tid & 7) ^ (srow & 7)) * 8;   // swizzled global col
    const f16* gA = A + (long)(i0 + srow) * lda + scol;
    const f16* gB = B + (long)(j0 + srow) * ldb + scol;
    f16* lA0 = Lds + tid * 8;
    f16* lB0 = Lds + 16384 + tid * 8;
    f16* lA1 = Lds + 32768 + tid * 8;
    f16* lB1 = Lds + 32768 + 16384 + tid * 8;

    // prologue: tile 0 -> buf0, issue order = steady staging order:
    // Bq0,Bq1,Bq2,Bq3,Aq0,Aq2,Aq1,Aq3; vmcnt(2) keeps Aq1,Aq3 in flight.
    gld_lds16(gB,                   lB0);
    gld_lds16(gB + (long)64 * ldb,  lB0 + 4096);
    gld_lds16(gB + (long)128 * ldb, lB0 + 8192);
    gld_lds16(gB + (long)192 * ldb, lB0 + 12288);
    gld_lds16(gA,                   lA0);
    gld_lds16(gA + (long)128 * lda, lA0 + 8192);
    gld_lds16(gA + (long)64 * lda,  lA0 + 4096);
    gld_lds16(gA + (long)192 * lda, lA0 + 12288);

    f32x4 acc[8][4] = {};

    asm volatile("s_waitcnt vmcnt(2)" ::: "memory");
    BARRIER();

    // 16 K-tiles: 7 steady pairs (tiles 0-13) + tile 14 (last stage) + tile 15
    for (int t = 0; t < 14; t += 2) {
        tile256<true, 2, 2>(acc, A0k0, A0k1, B0k0, B0k1,
                            gA + (t + 1) * 64, gB + (t + 1) * 64,
                            lA1, lB1, lda, ldb);
        tile256<true, 2, 2>(acc, A0k0 + 32768, A0k1 + 32768,
                            B0k0 + 32768, B0k1 + 32768,
                            gA + (t + 2) * 64, gB + (t + 2) * 64,
                            lA0, lB0, lda, ldb);
    }
    tile256<true, 2, 2>(acc, A0k0, A0k1, B0k0, B0k1,
                        gA + 15 * 64, gB + 15 * 64, lA1, lB1, lda, ldb);
    tile256<false, 0, -1>(acc, A0k0 + 32768, A0k1 + 32768,
                          B0k0 + 32768, B0k1 + 32768,
                          nullptr, nullptr, nullptr, nullptr, lda, ldb);

    // epilogue: C[row][col], col = lane&15, row = quad*4 + reg
    #pragma unroll
    for (int mf = 0; mf < 8; mf++) {
        const int r0 = i0 + wm * 128 + mf * 16 + quad * 4;
        #pragma unroll
        for (int nf = 0; nf < 4; nf++) {
            const int c = j0 + wn * 64 + nf * 16 + row16;
            #pragma unroll
            for (int r = 0; r < 4; r++)
                C[(long)(r0 + r) * ldc + c] = (f16)acc[mf][nf][r];
        }
    }
}

// ---------------------------------------------------------------------------
// 128x64x64 GEMM body, shared by the merged Vt+scores kernel and PV.
// 4 waves 2x2, each wave 64x32 out (acc[4][2]); ~48 VGPR / 24KB LDS -> 6+
// blocks/CU; cross-block overlap hides the 2-barrier drain stall.
// (r8: split-K atomics regressed 1.7x. r10: 1-block/CU lockstep fusion
//  regressed 2.5x. This engine lives and dies by independent-block TLP.)
// ---------------------------------------------------------------------------
template<typename OutT>
__device__ __forceinline__ void gemm128_body(
    const f16* __restrict__ A, const f16* __restrict__ B, OutT* __restrict__ C,
    int lda, int ldb, int ldc, int Keff, float scale, int i0, int j0)
{
    __shared__ f16 As[128 * 64] __attribute__((aligned(16)));
    __shared__ f16 Bs[64 * 64]  __attribute__((aligned(16)));

    const int tid  = threadIdx.x;
    const int lane = tid & 63;
    const int wave = tid >> 6;
    const int row16 = lane & 15;
    const int quad  = lane >> 4;
    const int swz   = row16 & 7;
    const int wr = (wave >> 1) * 64;   // wave row offset: 0 / 64
    const int wc = (wave & 1) * 32;    // wave col offset: 0 / 32

    const int srow = tid >> 3;                       // 0..31
    const int scol = ((tid & 7) ^ (srow & 7)) * 8;   // swizzled global col
    const f16* gA = A + (long)(i0 + srow) * lda + scol;
    const f16* gB = B + (long)(j0 + srow) * ldb + scol;
    f16* lA = As + tid * 8;   // + p*32*64
    f16* lB = Bs + tid * 8;

    f32x4 acc[4][2] = {};

    for (int k0 = 0; k0 < Keff; k0 += 64) {
        gld_lds16(gA + k0,                  lA);
        gld_lds16(gA + k0 + (long)32 * lda, lA + 32 * 64);
        gld_lds16(gA + k0 + (long)64 * lda, lA + 64 * 64);
        gld_lds16(gA + k0 + (long)96 * lda, lA + 96 * 64);
        gld_lds16(gB + k0,                  lB);
        gld_lds16(gB + k0 + (long)32 * ldb, lB + 32 * 64);
        __syncthreads();

        #pragma unroll
        for (int kk = 0; kk < 2; kk++) {
            f16x8 af[4], bf[2];
            #pragma unroll
            for (int t = 0; t < 4; t++)
                af[t] = *(const f16x8*)(As + (wr + t * 16 + row16) * 64
                                           + (((kk * 4 + quad) ^ swz) * 8));
            #pragma unroll
            for (int t = 0; t < 2; t++)
                bf[t] = *(const f16x8*)(Bs + (wc + t * 16 + row16) * 64
                                           + (((kk * 4 + quad) ^ swz) * 8));
            #pragma unroll
            for (int mt = 0; mt < 4; mt++)
                #pragma unroll
                for (int nt = 0; nt < 2; nt++)
                    acc[mt][nt] = __builtin_amdgcn_mfma_f32_16x16x32_f16(
                        af[mt], bf[nt], acc[mt][nt], 0, 0, 0);
        }
        __syncthreads();
    }

    // epilogue: C[row][col], col = lane&15, row = quad*4 + reg
    #pragma unroll
    for (int mt = 0; mt < 4; mt++) {
        const int r0 = i0 + wr + mt * 16 + quad * 4;
        #pragma unroll
        for (int nt = 0; nt < 2; nt++) {
            const int c = j0 + wc + nt * 16 + row16;
            #pragma unroll
            for (int r = 0; r < 4; r++)
                C[(long)(r0 + r) * ldc + c] = (OutT)(acc[mt][nt][r] * scale);
        }
    }
}

// Merged V^T + scores dispatch: 2112 uniform-work blocks (K=1024), with
// XCD-chunk swizzles (T1) so panel-sharing blocks land on one XCD's L2:
//  blocks [0,1024): V^T = Wv x^T. Logical order i-inner/j-outer (L = j*8+i);
//    chunk 128 logical tiles per XCD -> each xh B-panel (128KB, shared by the
//    8 i-blocks) is consumed within one XCD; wvh (2MB) is L2-resident.
//  blocks [1024,2112): Sc = Q K^T / 32, lower-tri 64-wide tiles (272/batch,
//    row-band-major); chunk 136 per XCD -> Q-panels fetched once per XCD.
//    Tile L -> XCD L/136: batch z's rows y=0..10 write through XCD 2z's L2,
//    y~11..15 through XCD 2z+1's (each chunk = 2.2MB < 4MB L2).
// Measured at the 128-engine structural floor (49.3 us, FETCH 47MB, r7/r9).
__global__ void __launch_bounds__(256)
gemm_vt_sc(const f16* __restrict__ xh, const f16* __restrict__ wvh,
           const f16* __restrict__ QKh, f16* __restrict__ Vt,
           f16* __restrict__ Sc)
{
    const int blk = (int)blockIdx.x;
    if (blk < 1024) {
        const int L = (blk & 7) * 128 + (blk >> 3);   // bijective: 1024 = 8*128
        const int j = L >> 3;                          // 0..127 (col tile)
        const int i = L & 7;                           // 0..7   (row tile)
        gemm128_body<f16>(wvh, xh, Vt, 1024, 1024, 8192, 1024, 1.f,
                          i * 128, j * 64);
    } else {
        const int m = blk - 1024;                      // 0..1087
        const int L = (m & 7) * 136 + (m >> 3);        // bijective: 1088 = 8*136
        const int z = L / 272;                         // batch
        const int r = L - z * 272;
        int y = 0;
        while ((y + 1) * (y + 2) <= r) y++;            // cum(y) = y(y+1); r <= 271
        const int x = r - y * (y + 1);
        const long off = (long)z * (2048L * 2048);
        gemm128_body<f16>(QKh + off, QKh + 1024 + off, Sc + off,
                          2048, 2048, 2048, 1024, 0.03125f, y * 128, x * 64);
    }
}

// PV: O = P V. A = P [2048,2048] (f16, batch z), B = Vt [1024][8192] with
// batch z's tokens at columns z*2048 (B base = Vt + z*2048, ldb=8192).
// Keff = i0+128 (P rows zero beyond the diagonal tile).
// GLOBAL LPT (r9-proven): 1-D grid of 1024; by=15-(n>>6) dispatches strictly
// descending Keff machine-wide; small blocks backfill the tail.
__global__ void __launch_bounds__(256)
gemm_pv(const f16* __restrict__ Sc, const f16* __restrict__ Vt,
        float* __restrict__ out)
{
    const int n  = (int)blockIdx.x;      // 0..1023
    const int by = 15 - (n >> 6);        // descending Keff
    const int rem = n & 63;
    const int x  = rem >> 2;             // 0..15
    const int z  = rem & 3;              // 0..3
    const int i0 = by * 128;
    const int Keff = i0 + 128;
    gemm128_body<float>(Sc + (long)z * (2048L * 2048),
                        Vt + (long)z * 2048,
                        out + (long)z * (2048L * 1024),
                        2048, 8192, 1024, Keff, 1.f, i0, x * 64);
}

// in-place causal softmax over fp16 scores; one block per row, 256 thr x 8
// cols; only the live prefix L = ((i>>7)+1)*128 is read/written.
// XCD-AFFINITY ordering (r12): block bid runs on XCD bid%8 (round-robin
// dispatch); map bid -> row so the reader lands on the XCD whose L2 holds
// that row's Sc tiles (written by gemm_vt_sc's chunking above):
//   k=bid&7, s=bid>>3, z=k>>1;
//   k even: i = s          (rows 0..1023, y 0..7   -> written via XCD 2z)
//   k odd : s<640 ? i=1408+s (y 11..15 -> XCD 2z+1) : i=1024+(s-640) (y 8..10)
// Bijective per batch; 81% of rows read from their home L2 IF L2 contents
// survive the kernel boundary (this round's experiment); else exactly neutral.
__global__ void __launch_bounds__(256)
softmax_causal(f16* __restrict__ Sc)
{
    const int bid = (int)blockIdx.x;     // 0..8191
    const int k = bid & 7;
    const int s = bid >> 3;              // 0..1023
    const long b = k >> 1;               // batch
    int i;
    if (!(k & 1)) i = s;
    else          i = (s < 640) ? (1408 + s) : (1024 + (s - 640));

    f16* row = Sc + ((b * 2048 + i) * 2048L);
    const int L = ((i >> 7) + 1) << 7;   // tile-aligned live row length

    const int tid = threadIdx.x;
    const int c0  = tid * 8;
    const int lane = tid & 63, wave = tid >> 6;
    const bool act = c0 < L;

    float v[8];
    float m = -3.4e38f;
    if (act) {
        f16x8 in = *(const f16x8*)(row + c0);
        #pragma unroll
        for (int j = 0; j < 8; j++) {
            const bool ok = (c0 + j) <= i;
            v[j] = ok ? (float)in[j] : -3.4e38f;
            m = fmaxf(m, v[j]);
        }
    }
    #pragma unroll
    for (int off = 32; off > 0; off >>= 1)
        m = fmaxf(m, __shfl_down(m, off, 64));
    __shared__ float redm[4];
    if (lane == 0) redm[wave] = m;
    __syncthreads();
    const float m0 = fmaxf(fmaxf(redm[0], redm[1]), fmaxf(redm[2], redm[3]));

    float e[8];
    float s2 = 0.f;
    if (act) {
        #pragma unroll
        for (int j = 0; j < 8; j++) {
            const bool ok = (c0 + j) <= i;
            e[j] = ok ? __expf(v[j] - m0) : 0.f;
            s2 += e[j];
        }
    }
    #pragma unroll
    for (int off = 32; off > 0; off >>= 1)
        s2 += __shfl_down(s2, off, 64);
    __shared__ float reds[4];
    if (lane == 0) reds[wave] = s2;
    __syncthreads();
    const float inv = 1.f / (reds[0] + reds[1] + reds[2] + reds[3]);

    if (act) {
        f16x8 o;
        #pragma unroll
        for (int j = 0; j < 8; j++) o[j] = (f16)(e[j] * inv);
        *(f16x8*)(row + c0) = o;
    }
}

// fused fp32->fp16 of x, Wq, Wk, Wv in one dispatch.
__global__ void __launch_bounds__(256)
convert_all(const float* __restrict__ x, const float* __restrict__ Wq,
            const float* __restrict__ Wk, const float* __restrict__ Wv,
            f16* __restrict__ xh, f16* __restrict__ wh)
{
    const long blk = blockIdx.x;
    const float* src;
    f16* dst;
    long base;
    if (blk < 4096)      { src = x;  dst = xh;                    base = blk * 2048; }
    else if (blk < 4608) { src = Wq; dst = wh;                    base = (blk - 4096) * 2048; }
    else if (blk < 5120) { src = Wk; dst = wh + 1024L * 1024;     base = (blk - 4608) * 2048; }
    else                 { src = Wv; dst = wh + 2L * 1024 * 1024; base = (blk - 5120) * 2048; }
    const long i = base + (long)threadIdx.x * 8;
    f32x4 a = *(const f32x4*)(src + i);
    f32x4 b = *(const f32x4*)(src + i + 4);
    f16x8 o;
    o[0] = (f16)a[0]; o[1] = (f16)a[1]; o[2] = (f16)a[2]; o[3] = (f16)a[3];
    o[4] = (f16)b[0]; o[5] = (f16)b[1]; o[6] = (f16)b[2]; o[7] = (f16)b[3];
    *(f16x8*)(dst + i) = o;
}

extern "C" void kernel_launch(void* const* d_in, const int* in_sizes, int n_in,
                              void* d_out, int out_size, void* d_ws, size_t ws_size,
                              hipStream_t stream)
{
    (void)in_sizes; (void)n_in; (void)out_size; (void)ws_size;
    const float* x  = (const float*)d_in[0];
    const float* Wq = (const float*)d_in[1];
    const float* Wk = (const float*)d_in[2];
    const float* Wv = (const float*)d_in[3];
    float* out = (float*)d_out;

    const long NX = 4L * 2048 * 1024;   // B*S*E = 8388608
    const long NW = 1024L * 1024;

    char* p = (char*)d_ws;
    f16* xh  = (f16*)p; p += NX * 2;
    f16* wh  = (f16*)p; p += 3 * NW * 2;            // Wq | Wk | Wv contiguous
    f16* QKh = (f16*)p; p += 2 * NX * 2;            // [8192][2048]: Q cols | K cols
    f16* Vt  = (f16*)p; p += NX * 2;                // [E=1024][B*S=8192]
    f16* Sc  = (f16*)p; p += 4L * 2048 * 2048 * 2;  // scores -> P in place
    f16* wvh = wh + 2L * NW;

    convert_all<<<5632, 256, 0, stream>>>(x, Wq, Wk, Wv, xh, wh);

    // QK = x [Wq;Wk]^T : [8192,2048] via 8-phase 256^2, XCD-chunk swizzled
    gemm256_k1024<<<256, 512, 0, stream>>>(
        xh, wh, QKh, 1024, 1024, 2048);

    // merged: V^T (1024 blocks) + Sc lower-tri (1088 blocks), XCD-chunked
    gemm_vt_sc<<<2112, 256, 0, stream>>>(xh, wvh, QKh, Vt, Sc);

    // causal softmax in place (live prefix only), XCD-affinity ordered
    softmax_causal<<<4 * 2048, 256, 0, stream>>>(Sc);

    // O = P V, global-LPT ordered (all largest-Keff blocks dispatch first)
    gemm_pv<<<1024, 256, 0, stream>>>(Sc, Vt, out);
}

// Round 13
// 211.972 us; speedup vs baseline: 1.9302x; 1.0353x over previous
//
#include <hip/hip_runtime.h>

typedef _Float16 f16;
typedef _Float16 f16x8 __attribute__((ext_vector_type(8)));
typedef float    f32x4 __attribute__((ext_vector_type(4)));

// async global->LDS, 16B per lane; LDS dest = wave-uniform base + lane*16.
// Global source address is per-lane arbitrary (we exploit this for swizzling).
__device__ __forceinline__ void gld_lds16(const void* g, void* l) {
    __builtin_amdgcn_global_load_lds((__attribute__((address_space(1))) void*)g,
                                     (__attribute__((address_space(3))) void*)l,
                                     16, 0, 0);
}

// compiler-barrier-wrapped s_barrier: LDS/global ops must not migrate across.
#define BARRIER() do { asm volatile("" ::: "memory"); \
                       __builtin_amdgcn_s_barrier();  \
                       asm volatile("" ::: "memory"); } while (0)

// ---------------------------------------------------------------------------
// 8-phase 256x256xBK64 GEMM tile-step (C = A * B^T, f16 out), K = 1024.
// See r4-r9: per-phase fragment reads (no spill); vmcnt(2) at end-ph1/ph4
// only — loads never drain to 0 in the main loop (T3+T4); setprio (T5).
// ---------------------------------------------------------------------------
template<bool STG, int VM1, int VM4>
__device__ __forceinline__ void tile256(
    f32x4 (&acc)[8][4],
    const f16* Ak0, const f16* Ak1, const f16* Bk0, const f16* Bk1,
    const f16* gAn, const f16* gBn,   // next-tile global bases (k-adjusted)
    f16* lAn, f16* lBn,               // next-tile LDS dests (other buffer)
    int lda, int ldb)
{
    // ---- phase 1: kk0, m-frags 0-3 ----
    {
        f16x8 a[4], b[4];
        #pragma unroll
        for (int mf = 0; mf < 4; mf++) a[mf] = *(const f16x8*)(Ak0 + mf * 1024);
        #pragma unroll
        for (int nf = 0; nf < 4; nf++) b[nf] = *(const f16x8*)(Bk0 + nf * 1024);
        if (STG) {
            gld_lds16(gBn,                  lBn);
            gld_lds16(gBn + (long)64 * ldb, lBn + 4096);
        }
        BARRIER();
        __builtin_amdgcn_s_setprio(1);
        #pragma unroll
        for (int mf = 0; mf < 4; mf++)
            #pragma unroll
            for (int nf = 0; nf < 4; nf++)
                acc[mf][nf] = __builtin_amdgcn_mfma_f32_16x16x32_f16(
                    a[mf], b[nf], acc[mf][nf], 0, 0, 0);
        __builtin_amdgcn_s_setprio(0);
        if (VM1 == 2)      asm volatile("s_waitcnt vmcnt(2)" ::: "memory");
        else if (VM1 == 0) asm volatile("s_waitcnt vmcnt(0)" ::: "memory");
        BARRIER();
        // ---- phase 2: kk0, m-frags 4-7 (b still live) ----
        f16x8 a2[4];
        #pragma unroll
        for (int mf = 0; mf < 4; mf++) a2[mf] = *(const f16x8*)(Ak0 + (mf + 4) * 1024);
        if (STG) {
            gld_lds16(gBn + (long)128 * ldb, lBn + 8192);
            gld_lds16(gBn + (long)192 * ldb, lBn + 12288);
        }
        BARRIER();
        __builtin_amdgcn_s_setprio(1);
        #pragma unroll
        for (int mf = 0; mf < 4; mf++)
            #pragma unroll
            for (int nf = 0; nf < 4; nf++)
                acc[mf + 4][nf] = __builtin_amdgcn_mfma_f32_16x16x32_f16(
                    a2[mf], b[nf], acc[mf + 4][nf], 0, 0, 0);
        __builtin_amdgcn_s_setprio(0);
        BARRIER();
    }
    // ---- phase 3: kk1, m-frags 0-3 ----
    {
        f16x8 a[4], b[4];
        #pragma unroll
        for (int mf = 0; mf < 4; mf++) a[mf] = *(const f16x8*)(Ak1 + mf * 1024);
        #pragma unroll
        for (int nf = 0; nf < 4; nf++) b[nf] = *(const f16x8*)(Bk1 + nf * 1024);
        if (STG) {
            gld_lds16(gAn,                   lAn);
            gld_lds16(gAn + (long)128 * lda, lAn + 8192);
        }
        BARRIER();
        __builtin_amdgcn_s_setprio(1);
        #pragma unroll
        for (int mf = 0; mf < 4; mf++)
            #pragma unroll
            for (int nf = 0; nf < 4; nf++)
                acc[mf][nf] = __builtin_amdgcn_mfma_f32_16x16x32_f16(
                    a[mf], b[nf], acc[mf][nf], 0, 0, 0);
        __builtin_amdgcn_s_setprio(0);
        BARRIER();
        // ---- phase 4: kk1, m-frags 4-7 ----
        f16x8 a2[4];
        #pragma unroll
        for (int mf = 0; mf < 4; mf++) a2[mf] = *(const f16x8*)(Ak1 + (mf + 4) * 1024);
        if (STG) {
            gld_lds16(gAn + (long)64 * lda,  lAn + 4096);
            gld_lds16(gAn + (long)192 * lda, lAn + 12288);
        }
        BARRIER();
        __builtin_amdgcn_s_setprio(1);
        #pragma unroll
        for (int mf = 0; mf < 4; mf++)
            #pragma unroll
            for (int nf = 0; nf < 4; nf++)
                acc[mf + 4][nf] = __builtin_amdgcn_mfma_f32_16x16x32_f16(
                    a2[mf], b[nf], acc[mf + 4][nf], 0, 0, 0);
        __builtin_amdgcn_s_setprio(0);
        if (VM4 == 2)      asm volatile("s_waitcnt vmcnt(2)" ::: "memory");
        else if (VM4 == 0) asm volatile("s_waitcnt vmcnt(0)" ::: "memory");
        BARRIER();
    }
}

// 256x256, K=1024 engine body (generalized from gemm256_k1024: i0/j0 passed).
// 512 thr = 8 waves (2Mx4N); LDS 128 KiB double-buffered, XOR-chunk swizzled.
__device__ __forceinline__ void gemm256_body(
    const f16* __restrict__ A, const f16* __restrict__ B, f16* __restrict__ C,
    int lda, int ldb, int ldc, int i0, int j0, f16* Lds, int tid)
{
    const int lane = tid & 63;
    const int wave = tid >> 6;
    const int wm = wave >> 2, wn = wave & 3;
    const int row16 = lane & 15, quad = lane >> 4;
    const int swz = row16 & 7;

    // per-thread LDS read bases (buf0; buf1 = +32768). chunk XOR-deswizzle:
    // LDS[row][cb] holds global chunk cb^(row&7) -> read chunk (k-chunk ^ swz).
    const int c0 = (quad ^ swz) * 8;           // kk0 chunk
    const int c1 = ((quad + 4) ^ swz) * 8;     // kk1 chunk
    const f16* A0k0 = Lds + (wm * 128 + row16) * 64 + c0;
    const f16* A0k1 = Lds + (wm * 128 + row16) * 64 + c1;
    const f16* B0k0 = Lds + 16384 + (wn * 64 + row16) * 64 + c0;
    const f16* B0k1 = Lds + 16384 + (wn * 64 + row16) * 64 + c1;

    // staging: 512 thr x 16B cover one 64-row quarter (64x64 f16) per issue.
    const int srow = tid >> 3;                       // 0..63
    const int scol = ((tid & 7) ^ (srow & 7)) * 8;   // swizzled global col
    const f16* gA = A + (long)(i0 + srow) * lda + scol;
    const f16* gB = B + (long)(j0 + srow) * ldb + scol;
    f16* lA0 = Lds + tid * 8;
    f16* lB0 = Lds + 16384 + tid * 8;
    f16* lA1 = Lds + 32768 + tid * 8;
    f16* lB1 = Lds + 32768 + 16384 + tid * 8;

    // prologue: tile 0 -> buf0, issue order = steady staging order:
    // Bq0,Bq1,Bq2,Bq3,Aq0,Aq2,Aq1,Aq3; vmcnt(2) keeps Aq1,Aq3 in flight.
    gld_lds16(gB,                   lB0);
    gld_lds16(gB + (long)64 * ldb,  lB0 + 4096);
    gld_lds16(gB + (long)128 * ldb, lB0 + 8192);
    gld_lds16(gB + (long)192 * ldb, lB0 + 12288);
    gld_lds16(gA,                   lA0);
    gld_lds16(gA + (long)128 * lda, lA0 + 8192);
    gld_lds16(gA + (long)64 * lda,  lA0 + 4096);
    gld_lds16(gA + (long)192 * lda, lA0 + 12288);

    f32x4 acc[8][4] = {};

    asm volatile("s_waitcnt vmcnt(2)" ::: "memory");
    BARRIER();

    // 16 K-tiles: 7 steady pairs (tiles 0-13) + tile 14 (last stage) + tile 15
    for (int t = 0; t < 14; t += 2) {
        tile256<true, 2, 2>(acc, A0k0, A0k1, B0k0, B0k1,
                            gA + (t + 1) * 64, gB + (t + 1) * 64,
                            lA1, lB1, lda, ldb);
        tile256<true, 2, 2>(acc, A0k0 + 32768, A0k1 + 32768,
                            B0k0 + 32768, B0k1 + 32768,
                            gA + (t + 2) * 64, gB + (t + 2) * 64,
                            lA0, lB0, lda, ldb);
    }
    tile256<true, 2, 2>(acc, A0k0, A0k1, B0k0, B0k1,
                        gA + 15 * 64, gB + 15 * 64, lA1, lB1, lda, ldb);
    tile256<false, 0, -1>(acc, A0k0 + 32768, A0k1 + 32768,
                          B0k0 + 32768, B0k1 + 32768,
                          nullptr, nullptr, nullptr, nullptr, lda, ldb);

    // epilogue: C[row][col], col = lane&15, row = quad*4 + reg
    #pragma unroll
    for (int mf = 0; mf < 8; mf++) {
        const int r0 = i0 + wm * 128 + mf * 16 + quad * 4;
        #pragma unroll
        for (int nf = 0; nf < 4; nf++) {
            const int c = j0 + wn * 64 + nf * 16 + row16;
            #pragma unroll
            for (int r = 0; r < 4; r++)
                C[(long)(r0 + r) * ldc + c] = (f16)acc[mf][nf][r];
        }
    }
}

// K' + V^T in one 256-block 256^2-engine dispatch (both K=1024, uniform):
//  blocks [0,128):  K' = xh * M^T : [8192,1024] (32 i x 4 j tiles).
//    XCD m&7 gets i-tiles 4k..4k+3, all j (M is 2MB, L2-resident everywhere).
//  blocks [128,256): V^T = Wv x^T : [1024,8192] (4 i x 32 j tiles).
//    XCD m&7 gets j-tiles 4k..4k+3, all i (wvh 2MB L2-resident).
// This replaces the old QK 256^2 dispatch AND moves Vt off the 730 TF
// 128-engine onto this ~1150 TF engine.
__global__ void __launch_bounds__(512, 2)
gemm_kv(const f16* __restrict__ xh, const f16* __restrict__ M,
        const f16* __restrict__ wvh, f16* __restrict__ Kp,
        f16* __restrict__ Vt)
{
    __shared__ f16 Lds[2 * 32768] __attribute__((aligned(16)));
    const int m = (int)blockIdx.x;
    if (m < 128) {
        const int T = (m & 7) * 16 + (m >> 3);   // bijective: 128 = 8*16
        const int i = T >> 2, j = T & 3;
        gemm256_body(xh, M, Kp, 1024, 1024, 1024,
                     i * 256, j * 256, Lds, (int)threadIdx.x);
    } else {
        const int mm = m - 128;
        const int T = (mm & 7) * 16 + (mm >> 3);
        const int i = T & 3, j = T >> 2;
        gemm256_body(wvh, xh, Vt, 1024, 1024, 8192,
                     i * 256, j * 256, Lds, (int)threadIdx.x);
    }
}

// ---------------------------------------------------------------------------
// 128x64x64 GEMM body (M-gemm, Sc, PV). 4 waves 2x2, acc[4][2]; ~48 VGPR /
// 24KB LDS -> 6+ blocks/CU; cross-block TLP hides the 2-barrier drain.
// (r8: split-K atomics regressed 1.7x. r10: 1-block/CU lockstep fusion
//  regressed 2.5x. This engine lives and dies by independent-block TLP.)
// ---------------------------------------------------------------------------
template<typename OutT>
__device__ __forceinline__ void gemm128_body(
    const f16* __restrict__ A, const f16* __restrict__ B, OutT* __restrict__ C,
    int lda, int ldb, int ldc, int Keff, float scale, int i0, int j0)
{
    __shared__ f16 As[128 * 64] __attribute__((aligned(16)));
    __shared__ f16 Bs[64 * 64]  __attribute__((aligned(16)));

    const int tid  = threadIdx.x;
    const int lane = tid & 63;
    const int wave = tid >> 6;
    const int row16 = lane & 15;
    const int quad  = lane >> 4;
    const int swz   = row16 & 7;
    const int wr = (wave >> 1) * 64;   // wave row offset: 0 / 64
    const int wc = (wave & 1) * 32;    // wave col offset: 0 / 32

    const int srow = tid >> 3;                       // 0..31
    const int scol = ((tid & 7) ^ (srow & 7)) * 8;   // swizzled global col
    const f16* gA = A + (long)(i0 + srow) * lda + scol;
    const f16* gB = B + (long)(j0 + srow) * ldb + scol;
    f16* lA = As + tid * 8;   // + p*32*64
    f16* lB = Bs + tid * 8;

    f32x4 acc[4][2] = {};

    for (int k0 = 0; k0 < Keff; k0 += 64) {
        gld_lds16(gA + k0,                  lA);
        gld_lds16(gA + k0 + (long)32 * lda, lA + 32 * 64);
        gld_lds16(gA + k0 + (long)64 * lda, lA + 64 * 64);
        gld_lds16(gA + k0 + (long)96 * lda, lA + 96 * 64);
        gld_lds16(gB + k0,                  lB);
        gld_lds16(gB + k0 + (long)32 * ldb, lB + 32 * 64);
        __syncthreads();

        #pragma unroll
        for (int kk = 0; kk < 2; kk++) {
            f16x8 af[4], bf[2];
            #pragma unroll
            for (int t = 0; t < 4; t++)
                af[t] = *(const f16x8*)(As + (wr + t * 16 + row16) * 64
                                           + (((kk * 4 + quad) ^ swz) * 8));
            #pragma unroll
            for (int t = 0; t < 2; t++)
                bf[t] = *(const f16x8*)(Bs + (wc + t * 16 + row16) * 64
                                           + (((kk * 4 + quad) ^ swz) * 8));
            #pragma unroll
            for (int mt = 0; mt < 4; mt++)
                #pragma unroll
                for (int nt = 0; nt < 2; nt++)
                    acc[mt][nt] = __builtin_amdgcn_mfma_f32_16x16x32_f16(
                        af[mt], bf[nt], acc[mt][nt], 0, 0, 0);
        }
        __syncthreads();
    }

    // epilogue: C[row][col], col = lane&15, row = quad*4 + reg
    #pragma unroll
    for (int mt = 0; mt < 4; mt++) {
        const int r0 = i0 + wr + mt * 16 + quad * 4;
        #pragma unroll
        for (int nt = 0; nt < 2; nt++) {
            const int c = j0 + wc + nt * 16 + row16;
            #pragma unroll
            for (int r = 0; r < 4; r++)
                C[(long)(r0 + r) * ldc + c] = (OutT)(acc[mt][nt][r] * scale);
        }
    }
}

// M = Wq^T * Wk = WqT * WkT^T : [1024,1024], K=1024. 128 blocks (8i x 16j).
// M[a][b] = sum_k Wq[k][a] Wk[k][b]. Tiny (2.1 GF, ~6 us at half-machine).
__global__ void __launch_bounds__(256)
gemm_m(const f16* __restrict__ wqt, const f16* __restrict__ wkt,
       f16* __restrict__ M)
{
    const int blk = (int)blockIdx.x;     // 0..127
    const int i = blk >> 4;              // 0..7
    const int j = blk & 15;              // 0..15
    gemm128_body<f16>(wqt, wkt, M, 1024, 1024, 1024, 1024, 1.f,
                      i * 128, j * 64);
}

// Sc = x K'^T / 32 per batch, causal lower-tri 64-wide tiles (272/batch).
// scores_ij = x_i (Wq^T Wk) x_j^T = x_i K'_j — algebraically identical to
// Q K^T; K' replaces the K projection (15 GF saved vs the old QK path).
// XCD-chunked: 1088 = 8*136, tile L -> XCD L/136 (same map as before, so
// the softmax affinity decode below still matches the writing XCD).
__global__ void __launch_bounds__(256)
gemm_sc(const f16* __restrict__ xh, const f16* __restrict__ Kp,
        f16* __restrict__ Sc)
{
    const int m = (int)blockIdx.x;                 // 0..1087
    const int L = (m & 7) * 136 + (m >> 3);        // bijective: 1088 = 8*136
    const int z = L / 272;                         // batch
    const int r = L - z * 272;
    int y = 0;
    while ((y + 1) * (y + 2) <= r) y++;            // cum(y) = y(y+1); r <= 271
    const int x = r - y * (y + 1);
    const long aoff = (long)z * (2048L * 1024);
    gemm128_body<f16>(xh + aoff, Kp + aoff, Sc + (long)z * (2048L * 2048),
                      1024, 1024, 2048, 1024, 0.03125f, y * 128, x * 64);
}

// PV: O = P V. A = P [2048,2048] (f16, batch z), B = Vt [1024][8192] with
// batch z's tokens at columns z*2048 (B base = Vt + z*2048, ldb=8192).
// Keff = i0+128 (P rows zero beyond the diagonal tile).
// GLOBAL LPT (r9-proven): by=15-(n>>6) dispatches strictly descending Keff
// machine-wide; small blocks backfill the tail.
__global__ void __launch_bounds__(256)
gemm_pv(const f16* __restrict__ Sc, const f16* __restrict__ Vt,
        float* __restrict__ out)
{
    const int n  = (int)blockIdx.x;      // 0..1023
    const int by = 15 - (n >> 6);        // descending Keff
    const int rem = n & 63;
    const int x  = rem >> 2;             // 0..15
    const int z  = rem & 3;              // 0..3
    const int i0 = by * 128;
    const int Keff = i0 + 128;
    gemm128_body<float>(Sc + (long)z * (2048L * 2048),
                        Vt + (long)z * 2048,
                        out + (long)z * (2048L * 1024),
                        2048, 8192, 1024, Keff, 1.f, i0, x * 64);
}

// in-place causal softmax over fp16 scores; one block per row, 256 thr x 8
// cols; only the live prefix L = ((i>>7)+1)*128 is read/written.
// XCD-affinity row ordering (r12: measured neutral, kept — harmless).
__global__ void __launch_bounds__(256)
softmax_causal(f16* __restrict__ Sc)
{
    const int bid = (int)blockIdx.x;     // 0..8191
    const int k = bid & 7;
    const int s = bid >> 3;              // 0..1023
    const long b = k >> 1;               // batch
    int i;
    if (!(k & 1)) i = s;
    else          i = (s < 640) ? (1408 + s) : (1024 + (s - 640));

    f16* row = Sc + ((b * 2048 + i) * 2048L);
    const int L = ((i >> 7) + 1) << 7;   // tile-aligned live row length

    const int tid = threadIdx.x;
    const int c0  = tid * 8;
    const int lane = tid & 63, wave = tid >> 6;
    const bool act = c0 < L;

    float v[8];
    float m = -3.4e38f;
    if (act) {
        f16x8 in = *(const f16x8*)(row + c0);
        #pragma unroll
        for (int j = 0; j < 8; j++) {
            const bool ok = (c0 + j) <= i;
            v[j] = ok ? (float)in[j] : -3.4e38f;
            m = fmaxf(m, v[j]);
        }
    }
    #pragma unroll
    for (int off = 32; off > 0; off >>= 1)
        m = fmaxf(m, __shfl_down(m, off, 64));
    __shared__ float redm[4];
    if (lane == 0) redm[wave] = m;
    __syncthreads();
    const float m0 = fmaxf(fmaxf(redm[0], redm[1]), fmaxf(redm[2], redm[3]));

    float e[8];
    float s2 = 0.f;
    if (act) {
        #pragma unroll
        for (int j = 0; j < 8; j++) {
            const bool ok = (c0 + j) <= i;
            e[j] = ok ? __expf(v[j] - m0) : 0.f;
            s2 += e[j];
        }
    }
    #pragma unroll
    for (int off = 32; off > 0; off >>= 1)
        s2 += __shfl_down(s2, off, 64);
    __shared__ float reds[4];
    if (lane == 0) reds[wave] = s2;
    __syncthreads();
    const float inv = 1.f / (reds[0] + reds[1] + reds[2] + reds[3]);

    if (act) {
        f16x8 o;
        #pragma unroll
        for (int j = 0; j < 8; j++) o[j] = (f16)(e[j] * inv);
        *(f16x8*)(row + c0) = o;
    }
}

// fused fp32->fp16 convert:
//  blocks [0,4096):     x -> xh (plain)
//  blocks [4096,4608):  Wv -> wvh (plain)
//  blocks [4608,5120):  Wq/Wk -> WqT/WkT, TRANSPOSED via 64x64 LDS tile
//    (WqT[e][k] = Wq[k][e], row-major — feeds gemm_m's A*B^T form).
__global__ void __launch_bounds__(256)
convert_all(const float* __restrict__ x, const float* __restrict__ Wq,
            const float* __restrict__ Wk, const float* __restrict__ Wv,
            f16* __restrict__ xh, f16* __restrict__ wvh,
            f16* __restrict__ wqt, f16* __restrict__ wkt)
{
    const long blk = blockIdx.x;
    if (blk < 4608) {
        const float* src;
        f16* dst;
        long base;
        if (blk < 4096) { src = x;  dst = xh;  base = blk * 2048; }
        else            { src = Wv; dst = wvh; base = (blk - 4096) * 2048; }
        const long i = base + (long)threadIdx.x * 8;
        f32x4 a = *(const f32x4*)(src + i);
        f32x4 b = *(const f32x4*)(src + i + 4);
        f16x8 o;
        o[0] = (f16)a[0]; o[1] = (f16)a[1]; o[2] = (f16)a[2]; o[3] = (f16)a[3];
        o[4] = (f16)b[0]; o[5] = (f16)b[1]; o[6] = (f16)b[2]; o[7] = (f16)b[3];
        *(f16x8*)(dst + i) = o;
    } else {
        const int tb = (int)blk - 4608;            // 0..511
        const float* W = (tb < 256) ? Wq : Wk;
        f16* O = (tb < 256) ? wqt : wkt;
        const int tt = tb & 255;
        const int k0 = (tt >> 4) * 64;             // 16 k-tiles
        const int e0 = (tt & 15) * 64;             // 16 e-tiles
        __shared__ f16 T[64][72] __attribute__((aligned(16)));  // 144B rows (16B-mult)
        const int t = (int)threadIdx.x;
        #pragma unroll
        for (int p = 0; p < 4; p++) {
            const int r = p * 16 + (t >> 4);       // 0..63 (k within tile)
            const int c = (t & 15) * 4;            // 0..60 (e within tile)
            f32x4 v = *(const f32x4*)(W + (long)(k0 + r) * 1024 + e0 + c);
            T[c + 0][r] = (f16)v[0];
            T[c + 1][r] = (f16)v[1];
            T[c + 2][r] = (f16)v[2];
            T[c + 3][r] = (f16)v[3];
        }
        __syncthreads();
        const int er = t >> 2;                     // 0..63 (e row of output)
        const int kc = (t & 3) * 16;               // 0..48 (k col chunk)
        f16x8 a = *(const f16x8*)(&T[er][kc]);
        f16x8 b = *(const f16x8*)(&T[er][kc + 8]);
        *(f16x8*)(O + (long)(e0 + er) * 1024 + k0 + kc)     = a;
        *(f16x8*)(O + (long)(e0 + er) * 1024 + k0 + kc + 8) = b;
    }
}

extern "C" void kernel_launch(void* const* d_in, const int* in_sizes, int n_in,
                              void* d_out, int out_size, void* d_ws, size_t ws_size,
                              hipStream_t stream)
{
    (void)in_sizes; (void)n_in; (void)out_size; (void)ws_size;
    const float* x  = (const float*)d_in[0];
    const float* Wq = (const float*)d_in[1];
    const float* Wk = (const float*)d_in[2];
    const float* Wv = (const float*)d_in[3];
    float* out = (float*)d_out;

    const long NX = 4L * 2048 * 1024;   // B*S*E = 8388608
    const long NW = 1024L * 1024;

    char* p = (char*)d_ws;
    f16* xh  = (f16*)p; p += NX * 2;                // 16 MB
    f16* wqt = (f16*)p; p += NW * 2;                // Wq^T  [E][KD]
    f16* wkt = (f16*)p; p += NW * 2;                // Wk^T  [E][KD]
    f16* wvh = (f16*)p; p += NW * 2;                // Wv    [E][E]
    f16* Mb  = (f16*)p; p += NW * 2;                // M = Wq^T Wk [KD... a][b]
    f16* Kp  = (f16*)p; p += NX * 2;                // K' = x M^T [8192][1024]
    f16* Vt  = (f16*)p; p += NX * 2;                // [E=1024][B*S=8192]
    f16* Sc  = (f16*)p; p += 4L * 2048 * 2048 * 2;  // scores -> P in place

    // converts (+ transposed Wq/Wk for the M-gemm's A*B^T form)
    convert_all<<<5120, 256, 0, stream>>>(x, Wq, Wk, Wv, xh, wvh, wqt, wkt);

    // M = Wq^T Wk : [1024,1024] (2.1 GF; enables dropping the K projection)
    gemm_m<<<128, 256, 0, stream>>>(wqt, wkt, Mb);

    // K' = x M^T (32x4 tiles) + V^T = Wv x^T (4x32 tiles): 256 blocks of the
    // 8-phase 256^2 engine, XCD-chunked
    gemm_kv<<<256, 512, 0, stream>>>(xh, Mb, wvh, Kp, Vt);

    // Sc = x K'^T / 32 per batch, lower-tri only (1088 blocks, XCD-chunked)
    gemm_sc<<<1088, 256, 0, stream>>>(xh, Kp, Sc);

    // causal softmax in place (live prefix only)
    softmax_causal<<<4 * 2048, 256, 0, stream>>>(Sc);

    // O = P V, global-LPT ordered
    gemm_pv<<<1024, 256, 0, stream>>>(Sc, Vt, out);
}